// Round 1
// 1914.048 us; speedup vs baseline: 1.0001x; 1.0001x over previous
//
#include <hip/hip_runtime.h>
#include <cstdint>
#include <cstddef>

typedef unsigned long long ull;
typedef unsigned int uint32;
typedef unsigned short u16;
typedef __attribute__((ext_vector_type(8))) short s8v;     // 8 bf16 (4 VGPR) MFMA frag
typedef __attribute__((ext_vector_type(4))) float f32x4;   // MFMA acc

// B=16, T=128, K=1024, D=768, KP=102
// R10: all-batch restructure.
//  fwd  = per-step 16x1024 @ 1024x1024 bf16 MFMA GEMM, 8 blocks (1/XCD),
//         state as bf16 hi/lo pairs in a 4-deep ring (2 MFMA passes ~ fp32).
//  vit  = 128 blocks x 8 cols x all batches, fp32 max-plus, LDS-staged state.
//  sync = per-producer sentinel words (poison-init), data ordered before the
//         sentinel by per-thread vmcnt drain at __syncthreads; ring-4 with
//         (t+2) re-poison (provably consumed, same argument as R9).
// 152 blocks <= 256 CUs: no CU hosts two sync-critical blocks.

#define POISON32 0xFFFFFFFFu
#define POISON64 0xFFFFFFFFFFFFFFFFull

// ---- workspace layout (4-byte word offsets) ----
#define OFF_EM    ((size_t)0)         // emission   2048*1024 f32
#define OFF_TR    ((size_t)2097152)   // transition 1024*1024 f32
#define OFF_EXPTB ((size_t)3145728)   // expTb      [i][j] bf16
#define OFF_UPP   ((size_t)3670016)   // fwd ring   4 slots * (hi+lo bf16 planes [m][k]) = 4*16384 words
#define OFF_APP   ((size_t)3735552)   // vit ring   4 slots * [i][b] f32
#define OFF_ULST  ((size_t)3801088)   // u at t=tb  16*1024 f32
#define OFF_ALST  ((size_t)3817472)   // av at t=tb 16*1024 f32
#define OFF_UALST ((size_t)3833856)   // ua at t=tb 16*102
#define OFF_ETOP  ((size_t)3835904)   // em_top 2048*102
#define OFF_ITOP  ((size_t)4044800)   // top_idx 2048*102
#define OFF_RMAX  ((size_t)4253696)
#define OFF_RLSE  ((size_t)4255744)
#define OFF_SMP   ((size_t)4257792)
#define OFF_BP    ((size_t)4259840)   // bp 128*16*1024 int
#define OFF_DONE  ((size_t)6356992)   // sentinels: F 4*8*16 + V 4*128*16 + VD 128*16 = 10752 u32
#define OFF_EXPTT ((size_t)6367744)   // expTbT [j][i] bf16 (524288 words)

__device__ __forceinline__ u16 f2bf(float f) {
  uint32 u = __builtin_bit_cast(uint32, f);
  u = (u + 0x7fffu + ((u >> 16) & 1u)) >> 16;
  return (u16)u;
}
__device__ __forceinline__ float bflo(uint32 w) {
  return __builtin_bit_cast(float, w << 16);
}
__device__ __forceinline__ float bfhi(uint32 w) {
  return __builtin_bit_cast(float, w & 0xffff0000u);
}
__device__ __forceinline__ void bfsplit(float v, u16& h, u16& l) {
  h = f2bf(v);
  float rh = __builtin_bit_cast(float, ((uint32)h) << 16);
  l = f2bf(v - rh);
}

// ---- coherent (cross-XCD) access helpers: relaxed agent-scope atomics ----
__device__ __forceinline__ ull load_bypass_u64(const ull* p) {
  return __hip_atomic_load(p, __ATOMIC_RELAXED, __HIP_MEMORY_SCOPE_AGENT);
}
__device__ __forceinline__ void store_bypass_u64(ull* p, ull v) {
  __hip_atomic_store(p, v, __ATOMIC_RELAXED, __HIP_MEMORY_SCOPE_AGENT);
}
__device__ __forceinline__ uint32 load_bypass_u32(const uint32* p) {
  return __hip_atomic_load(p, __ATOMIC_RELAXED, __HIP_MEMORY_SCOPE_AGENT);
}
__device__ __forceinline__ void store_bypass_u32(uint32* p, uint32 v) {
  __hip_atomic_store(p, v, __ATOMIC_RELAXED, __HIP_MEMORY_SCOPE_AGENT);
}
__device__ __forceinline__ void store_bypass_u16(u16* p, u16 v) {
  __hip_atomic_store(p, v, __ATOMIC_RELAXED, __HIP_MEMORY_SCOPE_AGENT);
}
__device__ __forceinline__ float load_bypass_f(const float* p) {
  return __hip_atomic_load(p, __ATOMIC_RELAXED, __HIP_MEMORY_SCOPE_AGENT);
}
__device__ __forceinline__ void store_bypass_f(float* p, float v) {
  __hip_atomic_store(p, v, __ATOMIC_RELAXED, __HIP_MEMORY_SCOPE_AGENT);
}
__device__ __forceinline__ void store_bypass_i(int* p, int v) {
  __hip_atomic_store(p, v, __ATOMIC_RELAXED, __HIP_MEMORY_SCOPE_AGENT);
}
__device__ __forceinline__ int load_bypass_i(const int* p) {
  return __hip_atomic_load(p, __ATOMIC_RELAXED, __HIP_MEMORY_SCOPE_AGENT);
}

// ---------------- GEMM: [x_emb; state] (3072x768) @ state^T -> 3072x1024 ----
__global__ __launch_bounds__(256) void gemm_kernel(
    const float* __restrict__ x, const float* __restrict__ stm,
    float* __restrict__ emission, float* __restrict__ transition,
    u16* __restrict__ expTb) {
  __shared__ float As[16][68];
  __shared__ float Bs[16][68];
  const int tid = threadIdx.x;
  const int tx = tid & 15, ty = tid >> 4;
  const int m0 = blockIdx.x * 64, n0 = blockIdx.y * 64;
  const int lr = tid >> 2;
  const int lc = (tid & 3) << 2;
  float acc[4][4] = {};
  const float* aptr;
  {
    int gr = m0 + lr;
    aptr = (gr < 2048) ? (x + (size_t)gr * 768) : (stm + (size_t)(gr - 2048) * 768);
  }
  const float* bptr = stm + (size_t)(n0 + lr) * 768;
  for (int k0 = 0; k0 < 768; k0 += 16) {
    float4 a4 = *(const float4*)(aptr + k0 + lc);
    float4 b4 = *(const float4*)(bptr + k0 + lc);
    __syncthreads();
    As[lc + 0][lr] = a4.x; As[lc + 1][lr] = a4.y; As[lc + 2][lr] = a4.z; As[lc + 3][lr] = a4.w;
    Bs[lc + 0][lr] = b4.x; Bs[lc + 1][lr] = b4.y; Bs[lc + 2][lr] = b4.z; Bs[lc + 3][lr] = b4.w;
    __syncthreads();
#pragma unroll
    for (int kk = 0; kk < 16; ++kk) {
      float a[4], b[4];
#pragma unroll
      for (int q = 0; q < 4; ++q) a[q] = As[kk][ty * 4 + q];
#pragma unroll
      for (int q = 0; q < 4; ++q) b[q] = Bs[kk][tx * 4 + q];
#pragma unroll
      for (int i2 = 0; i2 < 4; ++i2)
#pragma unroll
        for (int j2 = 0; j2 < 4; ++j2) acc[i2][j2] += a[i2] * b[j2];
    }
  }
  const float rs = 0.03608439182435161f;  // 1/sqrt(768)
#pragma unroll
  for (int i2 = 0; i2 < 4; ++i2) {
    int r = m0 + ty * 4 + i2;
#pragma unroll
    for (int j2 = 0; j2 < 4; ++j2) {
      int c = n0 + tx * 4 + j2;
      float v = acc[i2][j2] * rs;
      if (r < 2048) {
        emission[(size_t)r * 1024 + c] = v;
      } else {
        size_t o = (size_t)(r - 2048) * 1024 + c;
        transition[o] = v;
        expTb[o] = f2bf(expf(v));
      }
    }
  }
}

// ---------------- bf16 transpose: expTbT[j][i] = expTb[i][j] ----------------
__global__ __launch_bounds__(256) void transT_kernel(
    const u16* __restrict__ src, u16* __restrict__ dst) {
  __shared__ u16 tile[64][65];
  const int bx = blockIdx.x * 64, by = blockIdx.y * 64;
  const int tx = threadIdx.x & 63, ty4 = threadIdx.x >> 6;
  for (int rr = ty4; rr < 64; rr += 4)
    tile[rr][tx] = src[(size_t)(bx + rr) * 1024 + by + tx];
  __syncthreads();
  for (int rr = ty4; rr < 64; rr += 4)
    dst[(size_t)(by + rr) * 1024 + bx + tx] = tile[tx][rr];
}

// ---------------- per-row bitonic sort -> top-102 set, max, lse, argmax ----
__global__ __launch_bounds__(256) void topk_kernel(
    const float* __restrict__ emission, float* __restrict__ em_top,
    int* __restrict__ top_idx, float* __restrict__ row_max,
    float* __restrict__ row_lse, int* __restrict__ sm_pred) {
  __shared__ float v[1024];
  __shared__ int ix[1024];
  __shared__ float rb[256];
  const int row = blockIdx.x;
  const int tid = threadIdx.x;
  const float* e = emission + (size_t)row * 1024;
  for (int p = tid; p < 1024; p += 256) { v[p] = e[p]; ix[p] = p; }
  __syncthreads();
  for (int k = 2; k <= 1024; k <<= 1) {
    for (int j = k >> 1; j > 0; j >>= 1) {
      for (int p = tid; p < 1024; p += 256) {
        int l = p ^ j;
        if (l > p) {
          float va = v[p], vb = v[l];
          int ia = ix[p], ib = ix[l];
          bool aBefore = (va > vb) || (va == vb && ia < ib);
          bool up = ((p & k) == 0);
          if (up ? !aBefore : aBefore) { v[p] = vb; v[l] = va; ix[p] = ib; ix[l] = ia; }
        }
      }
      __syncthreads();
    }
  }
  float mx = v[0];
  float s = 0.f;
  for (int p = tid; p < 1024; p += 256) s += expf(v[p] - mx);
  rb[tid] = s; __syncthreads();
  for (int w = 128; w > 0; w >>= 1) { if (tid < w) rb[tid] += rb[tid + w]; __syncthreads(); }
  if (tid == 0) {
    row_max[row] = mx;
    row_lse[row] = mx + logf(rb[0]);
    sm_pred[row] = ix[0];
  }
  for (int p = tid; p < 102; p += 256) {
    em_top[(size_t)row * 102 + p] = v[p];
    top_idx[(size_t)row * 102 + p] = ix[p];
  }
}

// ---------------- poison the sentinel region (runs each launch) -------------
__global__ __launch_bounds__(256) void poison_kernel(ull* __restrict__ done8) {
  const int idx = blockIdx.x * 256 + threadIdx.x;   // 21*256 = 5376 = 10752 u32
  store_bypass_u64(done8 + idx, POISON64);
}

// ---------------- persistent all-batch scan ----------------
// grid 152 x 512: [0,8) fwd MFMA; [8,136) viterbi; [136,152) approx.
__global__ __launch_bounds__(512) void scan_kernel(
    const float* __restrict__ em, const float* __restrict__ tr,
    const u16* __restrict__ expTb, const u16* __restrict__ expTbT,
    const float* __restrict__ em_top, const int* __restrict__ top_idx,
    const int* __restrict__ y_lens,
    float* __restrict__ u_ring, float* __restrict__ av_ring,
    float* __restrict__ u_last, float* __restrict__ av_last,
    float* __restrict__ ua_last, int* __restrict__ bp,
    uint32* __restrict__ done, float* __restrict__ out_crf) {
  __shared__ ull SH[9232];                     // 73,856 B union (forces 1 block/CU)
  const int bid = blockIdx.x, tid = threadIdx.x;
  uint32* sentF = done;                        // [slot][p]  : slot*128 + p*16
  uint32* sentV = done + 512;                  // [slot][v]  : slot*2048 + v*16
  uint32* vdone = done + 8704;                 // [v]        : v*16

  if (bid < 8) {
    // ======== forward: block p owns cols [p*128, p*128+128), all 16 batches.
    // Per step: U_new = U * expT via mfma 16x16x32 bf16 (hi+lo passes), then
    // *exp(em)/1024, re-split to bf16 hi/lo, store to ring slot t&3.
    const int p = bid;
    int* stbF = (int*)(SH + 8192);             // LDS byte 65536 (past A-stage)
    if (tid < 16) stbF[tid] = y_lens[tid] - 1;
    const int l = tid & 63;
    const int lm = l & 15, lq = l >> 4;
    const int w2 = (tid >> 6) & 3;             // compute waves 0..3 (tid<256)
    // ---- t = 0 init: u0 = exp(em[:,0,:]) ----
    if (tid < 256) {
      const int m = tid >> 4;
      const int nn = p * 128 + ((tid & 15) << 3);
      const float* e0 = em + ((size_t)m << 17) + nn;
      u16* rh = (u16*)u_ring;                  // slot 0
      const bool last0 = (y_lens[m] == 1);
#pragma unroll
      for (int q = 0; q < 8; ++q) {
        float v = expf(e0[q]);
        u16 h, lo2; bfsplit(v, h, lo2);
        store_bypass_u16(rh + m * 1024 + nn + q, h);
        store_bypass_u16(rh + 16384 + m * 1024 + nn + q, lo2);
        if (last0) u_last[(size_t)m * 1024 + nn + q] = v;
      }
    }
    __syncthreads();
    if (tid == 0) {
      asm volatile("s_waitcnt vmcnt(0)" ::: "memory");
      store_bypass_u32(sentF + p * 16, 0u);
    }
    const char* Ab = (const char*)SH;
    const int offh = (lm << 11) + (lq << 4);   // A frag: m=lane&15 row, k-group lane>>4
    const int axor = (lm & 7) << 4;            // LDS XOR swizzle (2048B rows)
    const int nbase = p * 128 + w2 * 32;
    const u16* bq0 = expTbT + ((size_t)(nbase + lm) << 10) + (lq << 3);
    const u16* bq1 = bq0 + (16 << 10);
    for (int t = 1; t < 128; ++t) {
      if (tid < 8) {
        const uint32* sp = sentF + (size_t)((t - 1) & 3) * 128 + tid * 16;
        while (load_bypass_u32(sp) == POISON32) __builtin_amdgcn_s_sleep(1);
      }
      __syncthreads();
      if (tid == 0)   // re-poison slot t+2 (provably consumed: all passed t-2 polls)
        store_bypass_u32(sentF + (size_t)((t + 2) & 3) * 128 + p * 16, POISON32);
      {  // stage A (hi/lo planes, 64 KB) ring -> LDS, swizzled
        const ull* src = (const ull*)(u_ring + (size_t)((t - 1) & 3) * 16384);
        ull dbuf[16];
#pragma unroll
        for (int q = 0; q < 16; ++q) dbuf[q] = load_bypass_u64(src + tid + (q << 9));
#pragma unroll
        for (int q = 0; q < 16; ++q) {
          const int ob = (tid + (q << 9)) << 3;
          *(ull*)((char*)SH + (ob ^ (((ob >> 11) & 7) << 4))) = dbuf[q];
        }
      }
      __syncthreads();
      if (tid < 256) {
        f32x4 acc0a = {0.f, 0.f, 0.f, 0.f}, acc0b = {0.f, 0.f, 0.f, 0.f};
        f32x4 acc1a = {0.f, 0.f, 0.f, 0.f}, acc1b = {0.f, 0.f, 0.f, 0.f};
        for (int k0 = 0; k0 < 1024; k0 += 64) {
          const int o0 = (offh + (k0 << 1)) ^ axor;
          const int o1 = (offh + ((k0 + 32) << 1)) ^ axor;
          s8v ah0 = *(const s8v*)(Ab + o0);
          s8v al0 = *(const s8v*)(Ab + 32768 + o0);
          s8v ah1 = *(const s8v*)(Ab + o1);
          s8v al1 = *(const s8v*)(Ab + 32768 + o1);
          s8v b00 = *(const s8v*)(bq0 + k0);
          s8v b10 = *(const s8v*)(bq1 + k0);
          s8v b01 = *(const s8v*)(bq0 + k0 + 32);
          s8v b11 = *(const s8v*)(bq1 + k0 + 32);
          acc0a = __builtin_amdgcn_mfma_f32_16x16x32_bf16(ah0, b00, acc0a, 0, 0, 0);
          acc1a = __builtin_amdgcn_mfma_f32_16x16x32_bf16(ah0, b10, acc1a, 0, 0, 0);
          acc0b = __builtin_amdgcn_mfma_f32_16x16x32_bf16(ah1, b01, acc0b, 0, 0, 0);
          acc1b = __builtin_amdgcn_mfma_f32_16x16x32_bf16(ah1, b11, acc1b, 0, 0, 0);
          acc0a = __builtin_amdgcn_mfma_f32_16x16x32_bf16(al0, b00, acc0a, 0, 0, 0);
          acc1a = __builtin_amdgcn_mfma_f32_16x16x32_bf16(al0, b10, acc1a, 0, 0, 0);
          acc0b = __builtin_amdgcn_mfma_f32_16x16x32_bf16(al1, b01, acc0b, 0, 0, 0);
          acc1b = __builtin_amdgcn_mfma_f32_16x16x32_bf16(al1, b11, acc1b, 0, 0, 0);
        }
        u16* rh = (u16*)(u_ring + (size_t)(t & 3) * 16384);
        const float sc = 1.0f / 1024.0f;
#pragma unroll
        for (int r = 0; r < 4; ++r) {
          const int m = (lq << 2) + r;         // C/D: col=lane&15, row=(lane>>4)*4+r
          const size_t erow = (((size_t)m << 7) + t) << 10;
          {
            const int n = nbase + lm;
            float v = (acc0a[r] + acc0b[r]) * sc * expf(em[erow + n]);
            u16 h, lo2; bfsplit(v, h, lo2);
            store_bypass_u16(rh + m * 1024 + n, h);
            store_bypass_u16(rh + 16384 + m * 1024 + n, lo2);
            if (t == stbF[m]) u_last[(size_t)m * 1024 + n] = v;
          }
          {
            const int n = nbase + 16 + lm;
            float v = (acc1a[r] + acc1b[r]) * sc * expf(em[erow + n]);
            u16 h, lo2; bfsplit(v, h, lo2);
            store_bypass_u16(rh + m * 1024 + n, h);
            store_bypass_u16(rh + 16384 + m * 1024 + n, lo2);
            if (t == stbF[m]) u_last[(size_t)m * 1024 + n] = v;
          }
        }
        asm volatile("s_waitcnt vmcnt(0)" ::: "memory");
      }
      __syncthreads();
      if (tid == 0) store_bypass_u32(sentF + (size_t)(t & 3) * 128 + p * 16, 0u);
    }
  } else if (bid < 136) {
    // ======== viterbi: block v owns 8 cols (XCD-contiguous), all 16 batches.
    const int v = bid - 8;
    const int n0v = ((v & 7) << 7) + ((v >> 3) << 3);   // XCD v%8 gets cols [x*128,x*128+128)
    const int jj = tid & 7, g = tid >> 3;               // g in [0,64): 16 i's each
    const int col = n0v + jj;
    ull* ppb = (ull*)((char*)SH + 65536);               // partials [b][w][j] (val,idx)
    int* stb2 = (int*)((char*)SH + 73728);
    if (tid < 16) stb2[tid] = y_lens[tid] - 1;
    if (tid < 128) {                                    // t=0: av0 = em[:,0,:]
      const int jb = tid & 7, b = tid >> 3;
      const float e0 = em[((size_t)b << 17) + n0v + jb];
      store_bypass_f(av_ring + (size_t)(n0v + jb) * 16 + b, e0);
      if (y_lens[b] == 1) store_bypass_f(av_last + ((size_t)b << 10) + n0v + jb, e0);
    }
    __syncthreads();
    if (tid == 0) {
      asm volatile("s_waitcnt vmcnt(0)" ::: "memory");
      store_bypass_u32(sentV + v * 16, 0u);
    }
    const char* stc = (const char*)SH;                  // staged av [i][16] f32, swizzled
    for (int t = 1; t < 128; ++t) {
      if (tid < 128) {
        const uint32* sp = sentV + (size_t)((t - 1) & 3) * 2048 + tid * 16;
        while (load_bypass_u32(sp) == POISON32) __builtin_amdgcn_s_sleep(1);
      }
      __syncthreads();
      if (tid == 0)
        store_bypass_u32(sentV + (size_t)((t + 2) & 3) * 2048 + v * 16, POISON32);
      {  // stage av (64 KB) ring -> LDS, XOR-swizzled (64B rows; i-bits 4..6 -> bank bits)
        const ull* src = (const ull*)(av_ring + (size_t)((t - 1) & 3) * 16384);
        ull dbuf[16];
#pragma unroll
        for (int q = 0; q < 16; ++q) dbuf[q] = load_bypass_u64(src + tid + (q << 9));
#pragma unroll
        for (int q = 0; q < 16; ++q) {
          const int ob = (tid + (q << 9)) << 3;
          *(ull*)((char*)SH + (ob ^ (((ob >> 10) & 7) << 4))) = dbuf[q];
        }
      }
      __syncthreads();
      float mv[16]; int mi[16];
#pragma unroll
      for (int b = 0; b < 16; ++b) { mv[b] = -3.0e38f; mi[b] = 0x7fffffff; }
      const float* trc = tr + col;
      const int i0 = g << 4;
#pragma unroll 4
      for (int ii = 0; ii < 16; ++ii) {
        const int i = i0 + ii;
        const float tv = trc[(size_t)i << 10];
        const int ph = (i << 6) ^ (((i >> 4) & 7) << 4);
        const f32x4 s0 = *(const f32x4*)(stc + (ph ^ 0));
        const f32x4 s1 = *(const f32x4*)(stc + (ph ^ 16));
        const f32x4 s2 = *(const f32x4*)(stc + (ph ^ 32));
        const f32x4 s3 = *(const f32x4*)(stc + (ph ^ 48));
#pragma unroll
        for (int b = 0; b < 4; ++b) {
          float c0 = s0[b] + tv; if (c0 > mv[b])      { mv[b] = c0;      mi[b] = i; }
          float c1 = s1[b] + tv; if (c1 > mv[b + 4])  { mv[b + 4] = c1;  mi[b + 4] = i; }
          float c2 = s2[b] + tv; if (c2 > mv[b + 8])  { mv[b + 8] = c2;  mi[b + 8] = i; }
          float c3 = s3[b] + tv; if (c3 > mv[b + 12]) { mv[b + 12] = c3; mi[b + 12] = i; }
        }
      }
      // reduce over the wave's 8 g's (lane bits 3..5); ties -> lowest i
#pragma unroll
      for (int d = 8; d <= 32; d <<= 1) {
#pragma unroll
        for (int b = 0; b < 16; ++b) {
          float ov = __shfl_xor(mv[b], d);
          int oi = __shfl_xor(mi[b], d);
          if (ov > mv[b] || (ov == mv[b] && oi < mi[b])) { mv[b] = ov; mi[b] = oi; }
        }
      }
      if ((tid & 63) < 8) {
        const int wv = tid >> 6;
#pragma unroll
        for (int b = 0; b < 16; ++b) {
          ull pk = ((ull)(uint32)mi[b] << 32) | (ull)__builtin_bit_cast(uint32, mv[b]);
          ppb[(b << 6) + (wv << 3) + jj] = pk;
        }
      }
      __syncthreads();
      if (tid < 128) {
        const int jb = tid & 7, b = tid >> 3;
        const int cf = n0v + jb;
        float bmv = -3.0e38f; int bmi = 0x7fffffff;
#pragma unroll
        for (int w = 0; w < 8; ++w) {
          ull pk = ppb[(b << 6) + (w << 3) + jb];
          float pv = __builtin_bit_cast(float, (uint32)pk);
          int pi = (int)(pk >> 32);
          if (pv > bmv || (pv == bmv && pi < bmi)) { bmv = pv; bmi = pi; }
        }
        const float nv = bmv + em[((((size_t)b << 7) + t) << 10) + cf];
        store_bypass_f(av_ring + (size_t)(t & 3) * 16384 + (size_t)cf * 16 + b, nv);
        store_bypass_i(bp + ((size_t)t << 14) + ((size_t)b << 10) + cf, bmi);
        if (t == stb2[b]) store_bypass_f(av_last + ((size_t)b << 10) + cf, nv);
        asm volatile("s_waitcnt vmcnt(0)" ::: "memory");
      }
      __syncthreads();
      if (tid == 0) store_bypass_u32(sentV + (size_t)(t & 3) * 2048 + v * 16, 0u);
    }
    if (tid == 0) {
      asm volatile("s_waitcnt vmcnt(0)" ::: "memory");
      store_bypass_u32(vdone + v * 16, 0u);
    }
    // ---- backtrace: block v==0; one half-wave per batch ----
    if (v == 0) {
      if (tid < 128) {
        while (load_bypass_u32(vdone + tid * 16) == POISON32) __builtin_amdgcn_s_sleep(1);
      }
      __syncthreads();
      const int wv = tid >> 6, lh = tid & 63;
      const int hb = lh >> 5, hl = lh & 31;
      const int b = wv * 2 + hb;
      const int tbb = y_lens[b] - 1;
      for (int t2 = tbb + 1 + hl; t2 < 128; t2 += 32) out_crf[(b << 7) + t2] = 0.f;
      float bv = -3.0e38f; int bi = 0x7fffffff;
      for (int q = 0; q < 32; ++q) {
        const int i = (q << 5) + hl;
        const float val = load_bypass_f(av_last + ((size_t)b << 10) + i);
        if (val > bv || (val == bv && i < bi)) { bv = val; bi = i; }
      }
#pragma unroll
      for (int d = 1; d < 32; d <<= 1) {
        float ov = __shfl_xor(bv, d, 32);
        int oi = __shfl_xor(bi, d, 32);
        if (ov > bv || (ov == bv && oi < bi)) { bv = ov; bi = oi; }
      }
      if (hl == 0) {
        int sx = bi;
        out_crf[(b << 7) + tbb] = (float)sx;
        for (int t2 = tbb - 1; t2 >= 0; --t2) {
          sx = load_bypass_i(bp + ((size_t)(t2 + 1) << 14) + ((size_t)b << 10) + sx);
          out_crf[(b << 7) + t2] = (float)sx;
        }
      }
    }
  } else {
    // ======== approx: one block per batch, block-local (512 thr, 4 i-quarters)
    const int b = bid - 136;
    const int tb = y_lens[b] - 1;
    const int j2 = tid & 127, h2 = tid >> 7;
    float* sua0 = (float*)SH;
    float* sua1 = sua0 + 104;
    int* sidxp = (int*)(sua0 + 208);
    int* sidxc = sidxp + 104;
    float* aps = (float*)(sidxc + 104);        // 3*104
    if (tid < 102) {
      float vv = expf(em_top[(size_t)(b * 128) * 102 + tid]);
      sua0[tid] = vv;
      if (tb == 0) ua_last[b * 102 + tid] = vv;
    }
    __syncthreads();
    for (int t = 1; t < 128; ++t) {
      if (tid < 102) sidxp[tid] = top_idx[((size_t)b * 128 + (t - 1)) * 102 + tid];
      else if (tid >= 256 && tid < 358)
        sidxc[tid - 256] = top_idx[((size_t)b * 128 + t) * 102 + (tid - 256)];
      __syncthreads();
      float acc2 = 0.f;
      float* up = (t & 1) ? sua0 : sua1;
      float* cur = (t & 1) ? sua1 : sua0;
      if (j2 < 102) {
        const int colc = sidxc[j2];
        const int ia = h2 * 26;
        const int ib2 = (ia + 26 < 102) ? ia + 26 : 102;
        for (int i = ia; i < ib2; ++i)
          acc2 += up[i] * bflo((uint32)expTb[(size_t)sidxp[i] * 1024 + colc]);
      }
      if (h2 > 0 && j2 < 102) aps[(h2 - 1) * 104 + j2] = acc2;
      __syncthreads();
      if (h2 == 0 && j2 < 102) {
        acc2 += aps[j2] + aps[104 + j2] + aps[208 + j2];
        const float e = em_top[((size_t)b * 128 + t) * 102 + j2];
        const float nv = acc2 * expf(e) * (1.0f / 102.0f);
        cur[j2] = nv;
        if (t == tb) ua_last[b * 102 + j2] = nv;
      }
      __syncthreads();
    }
  }
}

// ---------------- scalars & metrics ----
__device__ __forceinline__ float blk_sum(float v, float* rb, int tid) {
  rb[tid] = v; __syncthreads();
  for (int w = 128; w > 0; w >>= 1) { if (tid < w) rb[tid] += rb[tid + w]; __syncthreads(); }
  float r = rb[0]; __syncthreads();
  return r;
}

__global__ __launch_bounds__(256) void finalize_kernel(
    const float* __restrict__ emission, const float* __restrict__ transition,
    const float* __restrict__ u_last, const float* __restrict__ ua_last,
    const float* __restrict__ row_max, const float* __restrict__ row_lse,
    const int* __restrict__ sm_pred, const int* __restrict__ y,
    const int* __restrict__ y_lens, float* __restrict__ d_out) {
  __shared__ float rb[256];
  __shared__ float sZ[16], sZa[16], sLogy[16];
  const int tid = threadIdx.x;
  const float* out_crf = d_out + 1;
  for (int b = 0; b < 16; ++b) {
    const int tb = y_lens[b] - 1;
    float p = 0.f;
    for (int i = tid; i < 1024; i += 256) p += u_last[(size_t)b * 1024 + i];
    p = blk_sum(p, rb, tid);
    if (tid == 0) sZ[b] = logf(p) + (float)tb * 6.931471805599453f;  // ln(1024)
    float q = 0.f;
    for (int i = tid; i < 102; i += 256) q += ua_last[(size_t)b * 102 + i];
    q = blk_sum(q, rb, tid);
    if (tid == 0) sZa[b] = logf(q) + (float)tb * 4.624972813284271f;  // ln(102)
  }
  if (tid < 16) sLogy[tid] = 0.f;
  __syncthreads();
  float a_local = 0, a_maxp = 0, c_sup = 0, c_pred = 0, c_ov = 0, c_match = 0;
  float s_predc = 0, s_ov = 0, s_match = 0;
  for (int r = tid; r < 2048; r += 256) {
    const int b = r >> 7, t = r & 127;
    const int L = y_lens[b];
    if (t < L) {
      const int yv = y[r];
      const float em_y = emission[(size_t)r * 1024 + yv];
      const float lse = row_lse[r];
      a_local += em_y - lse;
      a_maxp += expf(row_max[r] - lse);
      float term = em_y;
      if (t < L - 1) term += transition[(size_t)yv * 1024 + y[r + 1]];
      atomicAdd(&sLogy[b], term);
      const float ypos = (yv > 0) ? 1.f : 0.f;
      c_sup += ypos;
      const int cs = (int)out_crf[r];
      c_pred += (cs > 0) ? 1.f : 0.f;
      c_ov += ((cs > 0) && (yv > 0)) ? 1.f : 0.f;
      c_match += (cs == yv) ? 1.f : 0.f;
      const int ss = sm_pred[r];
      s_predc += (ss > 0) ? 1.f : 0.f;
      s_ov += ((ss > 0) && (yv > 0)) ? 1.f : 0.f;
      s_match += (ss == yv) ? 1.f : 0.f;
    }
  }
  __syncthreads();
  a_local = blk_sum(a_local, rb, tid);
  a_maxp = blk_sum(a_maxp, rb, tid);
  c_sup = blk_sum(c_sup, rb, tid);
  c_pred = blk_sum(c_pred, rb, tid);
  c_ov = blk_sum(c_ov, rb, tid);
  c_match = blk_sum(c_match, rb, tid);
  s_predc = blk_sum(s_predc, rb, tid);
  s_ov = blk_sum(s_ov, rb, tid);
  s_match = blk_sum(s_match, rb, tid);
  if (tid == 0) {
    float tl = 0.f;
    for (int b = 0; b < 16; ++b) tl += (float)y_lens[b];
    float mZ = 0, mZa = 0, dE = 0, dA = 0;
    for (int b = 0; b < 16; ++b) {
      mZ += sZ[b]; mZa += sZa[b];
      dE += sLogy[b] - sZ[b];
      dA += sLogy[b] - sZa[b];
    }
    mZ *= (1.f / 16.f); mZa *= (1.f / 16.f);
    const float sle = -dE * (1.f / 16.f);
    const float sla = -dA * (1.f / 16.f);
    const float slocal = a_local / tl;
    const float maxp = a_maxp / tl;
    const float loss = sla + 0.1f * slocal;
    const float crf_acc = c_match / tl;
    const float crf_prec = (c_pred > 0.f) ? (c_ov / fmaxf(c_pred, 1.f)) : 0.f;
    const float crf_recl = c_ov / fmaxf(c_sup, 1.f);
    const float crf_f1 = (crf_prec > 0.f)
        ? (2.f * crf_prec * crf_recl / fmaxf(crf_prec + crf_recl, 1e-12f)) : 0.f;
    const float sm_acc = s_match / tl;
    const float sm_prec = (s_predc > 0.f) ? (s_ov / fmaxf(s_predc, 1.f)) : 0.f;
    const float sm_recl = s_ov / fmaxf(c_sup, 1.f);
    const float sm_f1 = (sm_prec > 0.f)
        ? (2.f * sm_prec * sm_recl / fmaxf(sm_prec + sm_recl, 1e-12f)) : 0.f;
    d_out[0] = loss;
    d_out[2049] = mZ;
    d_out[2050] = mZa;
    d_out[2051] = sle;
    d_out[2052] = slocal;
    d_out[2053] = maxp;
    d_out[2054] = crf_acc;
    d_out[2055] = crf_f1;
    d_out[2056] = sm_acc;
    d_out[2057] = sm_f1;
  }
}

extern "C" void kernel_launch(void* const* d_in, const int* in_sizes, int n_in,
                              void* d_out, int out_size, void* d_ws, size_t ws_size,
                              hipStream_t stream) {
  const float* x = (const float*)d_in[0];
  const float* stm = (const float*)d_in[1];
  const int* y = (const int*)d_in[2];
  const int* yl = (const int*)d_in[3];
  float* out = (float*)d_out;
  float* ws = (float*)d_ws;

  float* emission = ws + OFF_EM;
  float* transition = ws + OFF_TR;
  u16* expTb = (u16*)(ws + OFF_EXPTB);
  u16* expTbT = (u16*)(ws + OFF_EXPTT);
  float* u_ring = ws + OFF_UPP;
  float* av_ring = ws + OFF_APP;
  float* u_last = ws + OFF_ULST;
  float* av_last = ws + OFF_ALST;
  float* ua_last = ws + OFF_UALST;
  float* em_top = ws + OFF_ETOP;
  int* top_idx = (int*)(ws + OFF_ITOP);
  float* row_max = ws + OFF_RMAX;
  float* row_lse = ws + OFF_RLSE;
  int* sm_pred = (int*)(ws + OFF_SMP);
  int* bp = (int*)(ws + OFF_BP);
  uint32* done = (uint32*)(ws + OFF_DONE);

  poison_kernel<<<21, 256, 0, stream>>>((ull*)done);
  gemm_kernel<<<dim3(48, 16), 256, 0, stream>>>(x, stm, emission, transition, expTb);
  transT_kernel<<<dim3(16, 16), 256, 0, stream>>>(expTb, expTbT);
  topk_kernel<<<2048, 256, 0, stream>>>(emission, em_top, top_idx, row_max, row_lse, sm_pred);
  scan_kernel<<<152, 512, 0, stream>>>(emission, transition, expTb, expTbT, em_top, top_idx,
                                       yl, u_ring, av_ring, u_last, av_last, ua_last,
                                       bp, done, out + 1);
  finalize_kernel<<<1, 256, 0, stream>>>(emission, transition, u_last, ua_last,
                                         row_max, row_lse, sm_pred, y, yl, out);
}

// Round 2
// 1902.291 us; speedup vs baseline: 1.0063x; 1.0062x over previous
//
#include <hip/hip_runtime.h>
#include <cstdint>
#include <cstddef>

typedef unsigned long long ull;
typedef unsigned int uint32;
typedef unsigned short u16;
typedef __attribute__((ext_vector_type(8))) short s8v;     // 8 bf16 (4 VGPR) MFMA frag
typedef __attribute__((ext_vector_type(4))) float f32x4;   // MFMA acc

// B=16, T=128, K=1024, D=768, KP=102
// R11: R10 compute structure unchanged; sync replaced by monotone per-slot
// counters (no poison, no per-producer sentinels).
//  - producers: per-thread vmcnt drain -> __syncthreads -> ONE fire-and-forget
//    agent atomic add per block per step (vit adds split over 8 cache lines).
//  - consumers: <=8 lanes poll the slot's counter lines until
//    cnt >= (((t-1)>>2)+1)*NP. Monotone => no reset / re-poison ever.
//  - ring-4 WAR safety: a block enters step t only after ALL blocks produced
//    t-1, so max skew = 1 step; slot t&3 was last read at step t-3.
//  - fixes R10 latent race: init stores now drained by EVERY storing wave
//    before the announce (was: only wave 0 drained).

// ---- workspace layout (4-byte word offsets) ----
#define OFF_EM    ((size_t)0)         // emission   2048*1024 f32
#define OFF_TR    ((size_t)2097152)   // transition 1024*1024 f32
#define OFF_EXPTB ((size_t)3145728)   // expTb      [i][j] bf16
#define OFF_UPP   ((size_t)3670016)   // fwd ring   4 slots * (hi+lo bf16 planes [m][k])
#define OFF_APP   ((size_t)3735552)   // vit ring   4 slots * [i][b] f32
#define OFF_ULST  ((size_t)3801088)   // u at t=tb  16*1024 f32
#define OFF_ALST  ((size_t)3817472)   // av at t=tb 16*1024 f32
#define OFF_UALST ((size_t)3833856)   // ua at t=tb 16*102
#define OFF_ETOP  ((size_t)3835904)   // em_top 2048*102
#define OFF_ITOP  ((size_t)4044800)   // top_idx 2048*102
#define OFF_RMAX  ((size_t)4253696)
#define OFF_RLSE  ((size_t)4255744)
#define OFF_SMP   ((size_t)4257792)
#define OFF_BP    ((size_t)4259840)   // bp 128*16*1024 int
#define OFF_DONE  ((size_t)6356992)   // counters: fcnt 4*16 | vcnt 32*16 | vdone
#define OFF_EXPTT ((size_t)6367744)   // expTbT [j][i] bf16 (524288 words)

__device__ __forceinline__ u16 f2bf(float f) {
  uint32 u = __builtin_bit_cast(uint32, f);
  u = (u + 0x7fffu + ((u >> 16) & 1u)) >> 16;
  return (u16)u;
}
__device__ __forceinline__ float bflo(uint32 w) {
  return __builtin_bit_cast(float, w << 16);
}
__device__ __forceinline__ float bfhi(uint32 w) {
  return __builtin_bit_cast(float, w & 0xffff0000u);
}
__device__ __forceinline__ void bfsplit(float v, u16& h, u16& l) {
  h = f2bf(v);
  float rh = __builtin_bit_cast(float, ((uint32)h) << 16);
  l = f2bf(v - rh);
}

// ---- coherent (cross-XCD) access helpers: relaxed agent-scope atomics ----
__device__ __forceinline__ ull load_bypass_u64(const ull* p) {
  return __hip_atomic_load(p, __ATOMIC_RELAXED, __HIP_MEMORY_SCOPE_AGENT);
}
__device__ __forceinline__ void store_bypass_u64(ull* p, ull v) {
  __hip_atomic_store(p, v, __ATOMIC_RELAXED, __HIP_MEMORY_SCOPE_AGENT);
}
__device__ __forceinline__ uint32 load_bypass_u32(const uint32* p) {
  return __hip_atomic_load(p, __ATOMIC_RELAXED, __HIP_MEMORY_SCOPE_AGENT);
}
__device__ __forceinline__ void store_bypass_u32(uint32* p, uint32 v) {
  __hip_atomic_store(p, v, __ATOMIC_RELAXED, __HIP_MEMORY_SCOPE_AGENT);
}
__device__ __forceinline__ void store_bypass_u16(u16* p, u16 v) {
  __hip_atomic_store(p, v, __ATOMIC_RELAXED, __HIP_MEMORY_SCOPE_AGENT);
}
__device__ __forceinline__ float load_bypass_f(const float* p) {
  return __hip_atomic_load(p, __ATOMIC_RELAXED, __HIP_MEMORY_SCOPE_AGENT);
}
__device__ __forceinline__ void store_bypass_f(float* p, float v) {
  __hip_atomic_store(p, v, __ATOMIC_RELAXED, __HIP_MEMORY_SCOPE_AGENT);
}
__device__ __forceinline__ void store_bypass_i(int* p, int v) {
  __hip_atomic_store(p, v, __ATOMIC_RELAXED, __HIP_MEMORY_SCOPE_AGENT);
}
__device__ __forceinline__ int load_bypass_i(const int* p) {
  return __hip_atomic_load(p, __ATOMIC_RELAXED, __HIP_MEMORY_SCOPE_AGENT);
}
__device__ __forceinline__ void cnt_add(uint32* p) {
  __hip_atomic_fetch_add(p, 1u, __ATOMIC_RELAXED, __HIP_MEMORY_SCOPE_AGENT);
}

// ---------------- GEMM: [x_emb; state] (3072x768) @ state^T -> 3072x1024 ----
__global__ __launch_bounds__(256) void gemm_kernel(
    const float* __restrict__ x, const float* __restrict__ stm,
    float* __restrict__ emission, float* __restrict__ transition,
    u16* __restrict__ expTb) {
  __shared__ float As[16][68];
  __shared__ float Bs[16][68];
  const int tid = threadIdx.x;
  const int tx = tid & 15, ty = tid >> 4;
  const int m0 = blockIdx.x * 64, n0 = blockIdx.y * 64;
  const int lr = tid >> 2;
  const int lc = (tid & 3) << 2;
  float acc[4][4] = {};
  const float* aptr;
  {
    int gr = m0 + lr;
    aptr = (gr < 2048) ? (x + (size_t)gr * 768) : (stm + (size_t)(gr - 2048) * 768);
  }
  const float* bptr = stm + (size_t)(n0 + lr) * 768;
  for (int k0 = 0; k0 < 768; k0 += 16) {
    float4 a4 = *(const float4*)(aptr + k0 + lc);
    float4 b4 = *(const float4*)(bptr + k0 + lc);
    __syncthreads();
    As[lc + 0][lr] = a4.x; As[lc + 1][lr] = a4.y; As[lc + 2][lr] = a4.z; As[lc + 3][lr] = a4.w;
    Bs[lc + 0][lr] = b4.x; Bs[lc + 1][lr] = b4.y; Bs[lc + 2][lr] = b4.z; Bs[lc + 3][lr] = b4.w;
    __syncthreads();
#pragma unroll
    for (int kk = 0; kk < 16; ++kk) {
      float a[4], b[4];
#pragma unroll
      for (int q = 0; q < 4; ++q) a[q] = As[kk][ty * 4 + q];
#pragma unroll
      for (int q = 0; q < 4; ++q) b[q] = Bs[kk][tx * 4 + q];
#pragma unroll
      for (int i2 = 0; i2 < 4; ++i2)
#pragma unroll
        for (int j2 = 0; j2 < 4; ++j2) acc[i2][j2] += a[i2] * b[j2];
    }
  }
  const float rs = 0.03608439182435161f;  // 1/sqrt(768)
#pragma unroll
  for (int i2 = 0; i2 < 4; ++i2) {
    int r = m0 + ty * 4 + i2;
#pragma unroll
    for (int j2 = 0; j2 < 4; ++j2) {
      int c = n0 + tx * 4 + j2;
      float v = acc[i2][j2] * rs;
      if (r < 2048) {
        emission[(size_t)r * 1024 + c] = v;
      } else {
        size_t o = (size_t)(r - 2048) * 1024 + c;
        transition[o] = v;
        expTb[o] = f2bf(expf(v));
      }
    }
  }
}

// ---------------- bf16 transpose: expTbT[j][i] = expTb[i][j] ----------------
__global__ __launch_bounds__(256) void transT_kernel(
    const u16* __restrict__ src, u16* __restrict__ dst) {
  __shared__ u16 tile[64][65];
  const int bx = blockIdx.x * 64, by = blockIdx.y * 64;
  const int tx = threadIdx.x & 63, ty4 = threadIdx.x >> 6;
  for (int rr = ty4; rr < 64; rr += 4)
    tile[rr][tx] = src[(size_t)(bx + rr) * 1024 + by + tx];
  __syncthreads();
  for (int rr = ty4; rr < 64; rr += 4)
    dst[(size_t)(by + rr) * 1024 + bx + tx] = tile[tx][rr];
}

// ---------------- per-row bitonic sort -> top-102 set, max, lse, argmax ----
__global__ __launch_bounds__(256) void topk_kernel(
    const float* __restrict__ emission, float* __restrict__ em_top,
    int* __restrict__ top_idx, float* __restrict__ row_max,
    float* __restrict__ row_lse, int* __restrict__ sm_pred) {
  __shared__ float v[1024];
  __shared__ int ix[1024];
  __shared__ float rb[256];
  const int row = blockIdx.x;
  const int tid = threadIdx.x;
  const float* e = emission + (size_t)row * 1024;
  for (int p = tid; p < 1024; p += 256) { v[p] = e[p]; ix[p] = p; }
  __syncthreads();
  for (int k = 2; k <= 1024; k <<= 1) {
    for (int j = k >> 1; j > 0; j >>= 1) {
      for (int p = tid; p < 1024; p += 256) {
        int l = p ^ j;
        if (l > p) {
          float va = v[p], vb = v[l];
          int ia = ix[p], ib = ix[l];
          bool aBefore = (va > vb) || (va == vb && ia < ib);
          bool up = ((p & k) == 0);
          if (up ? !aBefore : aBefore) { v[p] = vb; v[l] = va; ix[p] = ib; ix[l] = ia; }
        }
      }
      __syncthreads();
    }
  }
  float mx = v[0];
  float s = 0.f;
  for (int p = tid; p < 1024; p += 256) s += expf(v[p] - mx);
  rb[tid] = s; __syncthreads();
  for (int w = 128; w > 0; w >>= 1) { if (tid < w) rb[tid] += rb[tid + w]; __syncthreads(); }
  if (tid == 0) {
    row_max[row] = mx;
    row_lse[row] = mx + logf(rb[0]);
    sm_pred[row] = ix[0];
  }
  for (int p = tid; p < 102; p += 256) {
    em_top[(size_t)row * 102 + p] = v[p];
    top_idx[(size_t)row * 102 + p] = ix[p];
  }
}

// ---------------- zero the counter region (runs each launch) ----------------
__global__ __launch_bounds__(256) void zero_kernel(uint32* __restrict__ done) {
  const int idx = blockIdx.x * 256 + threadIdx.x;   // 4*256 = 1024 words
  store_bypass_u32(done + idx, 0u);
}

// ---------------- persistent all-batch scan ----------------
// grid 152 x 512: [0,8) fwd MFMA; [8,136) viterbi; [136,152) approx.
__global__ __launch_bounds__(512) void scan_kernel(
    const float* __restrict__ em, const float* __restrict__ tr,
    const u16* __restrict__ expTb, const u16* __restrict__ expTbT,
    const float* __restrict__ em_top, const int* __restrict__ top_idx,
    const int* __restrict__ y_lens,
    float* __restrict__ u_ring, float* __restrict__ av_ring,
    float* __restrict__ u_last, float* __restrict__ av_last,
    float* __restrict__ ua_last, int* __restrict__ bp,
    uint32* __restrict__ done, float* __restrict__ out_crf) {
  __shared__ ull SH[9232];                     // 73,856 B union (forces 1 block/CU)
  const int bid = blockIdx.x, tid = threadIdx.x;
  uint32* cntF = done;                         // fcnt[slot]      at done[slot*16]
  uint32* cntV = done + 64;                    // vcnt[slot][ln]  at done[64+(slot*8+ln)*16]
  uint32* vdone = done + 640;                  // single word

  if (bid < 8) {
    // ======== forward: block p owns cols [p*128, p*128+128), all 16 batches.
    const int p = bid;
    int* stbF = (int*)(SH + 8192);             // LDS byte 65536 (past A-stage)
    if (tid < 16) stbF[tid] = y_lens[tid] - 1;
    const int l = tid & 63;
    const int lm = l & 15, lq = l >> 4;
    const int w2 = (tid >> 6) & 3;             // compute waves 0..3 (tid<256)
    // ---- t = 0 init: u0 = exp(em[:,0,:]) ----
    if (tid < 256) {
      const int m = tid >> 4;
      const int nn = p * 128 + ((tid & 15) << 3);
      const float* e0 = em + ((size_t)m << 17) + nn;
      u16* rh = (u16*)u_ring;                  // slot 0
      const bool last0 = (y_lens[m] == 1);
#pragma unroll
      for (int q = 0; q < 8; ++q) {
        float v = expf(e0[q]);
        u16 h, lo2; bfsplit(v, h, lo2);
        store_bypass_u16(rh + m * 1024 + nn + q, h);
        store_bypass_u16(rh + 16384 + m * 1024 + nn + q, lo2);
        if (last0) u_last[(size_t)m * 1024 + nn + q] = v;
      }
      asm volatile("s_waitcnt vmcnt(0)" ::: "memory");   // drain in EVERY storing wave
    }
    __syncthreads();
    if (tid == 0) cnt_add(cntF + 0);
    const char* Ab = (const char*)SH;
    const int offh = (lm << 11) + (lq << 4);   // A frag: m=lane&15 row, k-group lane>>4
    const int axor = (lm & 7) << 4;            // LDS XOR swizzle (2048B rows)
    const int nbase = p * 128 + w2 * 32;
    const u16* bq0 = expTbT + ((size_t)(nbase + lm) << 10) + (lq << 3);
    const u16* bq1 = bq0 + (16 << 10);
    for (int t = 1; t < 128; ++t) {
      if (tid == 0) {
        const uint32 tgt = (uint32)((((t - 1) >> 2) + 1) * 8);
        const uint32* cp = cntF + (((t - 1) & 3) << 4);
        while (load_bypass_u32(cp) < tgt) __builtin_amdgcn_s_sleep(1);
      }
      __syncthreads();
      {  // stage A (hi/lo planes, 64 KB) ring -> LDS, swizzled
        const ull* src = (const ull*)(u_ring + (size_t)((t - 1) & 3) * 16384);
        ull dbuf[16];
#pragma unroll
        for (int q = 0; q < 16; ++q) dbuf[q] = load_bypass_u64(src + tid + (q << 9));
#pragma unroll
        for (int q = 0; q < 16; ++q) {
          const int ob = (tid + (q << 9)) << 3;
          *(ull*)((char*)SH + (ob ^ (((ob >> 11) & 7) << 4))) = dbuf[q];
        }
      }
      __syncthreads();
      if (tid < 256) {
        f32x4 acc0a = {0.f, 0.f, 0.f, 0.f}, acc0b = {0.f, 0.f, 0.f, 0.f};
        f32x4 acc1a = {0.f, 0.f, 0.f, 0.f}, acc1b = {0.f, 0.f, 0.f, 0.f};
        for (int k0 = 0; k0 < 1024; k0 += 64) {
          const int o0 = (offh + (k0 << 1)) ^ axor;
          const int o1 = (offh + ((k0 + 32) << 1)) ^ axor;
          s8v ah0 = *(const s8v*)(Ab + o0);
          s8v al0 = *(const s8v*)(Ab + 32768 + o0);
          s8v ah1 = *(const s8v*)(Ab + o1);
          s8v al1 = *(const s8v*)(Ab + 32768 + o1);
          s8v b00 = *(const s8v*)(bq0 + k0);
          s8v b10 = *(const s8v*)(bq1 + k0);
          s8v b01 = *(const s8v*)(bq0 + k0 + 32);
          s8v b11 = *(const s8v*)(bq1 + k0 + 32);
          acc0a = __builtin_amdgcn_mfma_f32_16x16x32_bf16(ah0, b00, acc0a, 0, 0, 0);
          acc1a = __builtin_amdgcn_mfma_f32_16x16x32_bf16(ah0, b10, acc1a, 0, 0, 0);
          acc0b = __builtin_amdgcn_mfma_f32_16x16x32_bf16(ah1, b01, acc0b, 0, 0, 0);
          acc1b = __builtin_amdgcn_mfma_f32_16x16x32_bf16(ah1, b11, acc1b, 0, 0, 0);
          acc0a = __builtin_amdgcn_mfma_f32_16x16x32_bf16(al0, b00, acc0a, 0, 0, 0);
          acc1a = __builtin_amdgcn_mfma_f32_16x16x32_bf16(al0, b10, acc1a, 0, 0, 0);
          acc0b = __builtin_amdgcn_mfma_f32_16x16x32_bf16(al1, b01, acc0b, 0, 0, 0);
          acc1b = __builtin_amdgcn_mfma_f32_16x16x32_bf16(al1, b11, acc1b, 0, 0, 0);
        }
        u16* rh = (u16*)(u_ring + (size_t)(t & 3) * 16384);
        const float sc = 1.0f / 1024.0f;
#pragma unroll
        for (int r = 0; r < 4; ++r) {
          const int m = (lq << 2) + r;         // C/D: col=lane&15, row=(lane>>4)*4+r
          const size_t erow = (((size_t)m << 7) + t) << 10;
          {
            const int n = nbase + lm;
            float v = (acc0a[r] + acc0b[r]) * sc * expf(em[erow + n]);
            u16 h, lo2; bfsplit(v, h, lo2);
            store_bypass_u16(rh + m * 1024 + n, h);
            store_bypass_u16(rh + 16384 + m * 1024 + n, lo2);
            if (t == stbF[m]) u_last[(size_t)m * 1024 + n] = v;
          }
          {
            const int n = nbase + 16 + lm;
            float v = (acc1a[r] + acc1b[r]) * sc * expf(em[erow + n]);
            u16 h, lo2; bfsplit(v, h, lo2);
            store_bypass_u16(rh + m * 1024 + n, h);
            store_bypass_u16(rh + 16384 + m * 1024 + n, lo2);
            if (t == stbF[m]) u_last[(size_t)m * 1024 + n] = v;
          }
        }
        asm volatile("s_waitcnt vmcnt(0)" ::: "memory");
      }
      __syncthreads();
      if (tid == 0) cnt_add(cntF + ((t & 3) << 4));
    }
  } else if (bid < 136) {
    // ======== viterbi: block v owns 8 cols (XCD-contiguous), all 16 batches.
    const int v = bid - 8;
    const int n0v = ((v & 7) << 7) + ((v >> 3) << 3);   // XCD v%8 gets cols [x*128,x*128+128)
    const int jj = tid & 7, g = tid >> 3;               // g in [0,64): 16 i's each
    const int col = n0v + jj;
    ull* ppb = (ull*)((char*)SH + 65536);               // partials [b][w][j] (val,idx)
    int* stb2 = (int*)((char*)SH + 73728);
    if (tid < 16) stb2[tid] = y_lens[tid] - 1;
    if (tid < 128) {                                    // t=0: av0 = em[:,0,:]
      const int jb = tid & 7, b = tid >> 3;
      const float e0 = em[((size_t)b << 17) + n0v + jb];
      store_bypass_f(av_ring + (size_t)(n0v + jb) * 16 + b, e0);
      if (y_lens[b] == 1) store_bypass_f(av_last + ((size_t)b << 10) + n0v + jb, e0);
      asm volatile("s_waitcnt vmcnt(0)" ::: "memory");  // drain in EVERY storing wave
    }
    __syncthreads();
    if (tid == 0) cnt_add(cntV + ((v & 7) << 4));       // slot 0, line v&7
    const char* stc = (const char*)SH;                  // staged av [i][16] f32, swizzled
    for (int t = 1; t < 128; ++t) {
      if (tid < 8) {
        const uint32 tgt = (uint32)((((t - 1) >> 2) + 1) * 16);
        const uint32* cp = cntV + (((((t - 1) & 3) << 3) + tid) << 4);
        while (load_bypass_u32(cp) < tgt) __builtin_amdgcn_s_sleep(1);
      }
      __syncthreads();
      {  // stage av (64 KB) ring -> LDS, XOR-swizzled (64B rows; i-bits 4..6 -> bank bits)
        const ull* src = (const ull*)(av_ring + (size_t)((t - 1) & 3) * 16384);
        ull dbuf[16];
#pragma unroll
        for (int q = 0; q < 16; ++q) dbuf[q] = load_bypass_u64(src + tid + (q << 9));
#pragma unroll
        for (int q = 0; q < 16; ++q) {
          const int ob = (tid + (q << 9)) << 3;
          *(ull*)((char*)SH + (ob ^ (((ob >> 10) & 7) << 4))) = dbuf[q];
        }
      }
      __syncthreads();
      float mv[16]; int mi[16];
#pragma unroll
      for (int b = 0; b < 16; ++b) { mv[b] = -3.0e38f; mi[b] = 0x7fffffff; }
      const float* trc = tr + col;
      const int i0 = g << 4;
#pragma unroll 4
      for (int ii = 0; ii < 16; ++ii) {
        const int i = i0 + ii;
        const float tv = trc[(size_t)i << 10];
        const int ph = (i << 6) ^ (((i >> 4) & 7) << 4);
        const f32x4 s0 = *(const f32x4*)(stc + (ph ^ 0));
        const f32x4 s1 = *(const f32x4*)(stc + (ph ^ 16));
        const f32x4 s2 = *(const f32x4*)(stc + (ph ^ 32));
        const f32x4 s3 = *(const f32x4*)(stc + (ph ^ 48));
#pragma unroll
        for (int b = 0; b < 4; ++b) {
          float c0 = s0[b] + tv; if (c0 > mv[b])      { mv[b] = c0;      mi[b] = i; }
          float c1 = s1[b] + tv; if (c1 > mv[b + 4])  { mv[b + 4] = c1;  mi[b + 4] = i; }
          float c2 = s2[b] + tv; if (c2 > mv[b + 8])  { mv[b + 8] = c2;  mi[b + 8] = i; }
          float c3 = s3[b] + tv; if (c3 > mv[b + 12]) { mv[b + 12] = c3; mi[b + 12] = i; }
        }
      }
      // reduce over the wave's 8 g's (lane bits 3..5); ties -> lowest i
#pragma unroll
      for (int d = 8; d <= 32; d <<= 1) {
#pragma unroll
        for (int b = 0; b < 16; ++b) {
          float ov = __shfl_xor(mv[b], d);
          int oi = __shfl_xor(mi[b], d);
          if (ov > mv[b] || (ov == mv[b] && oi < mi[b])) { mv[b] = ov; mi[b] = oi; }
        }
      }
      if ((tid & 63) < 8) {
        const int wv = tid >> 6;
#pragma unroll
        for (int b = 0; b < 16; ++b) {
          ull pk = ((ull)(uint32)mi[b] << 32) | (ull)__builtin_bit_cast(uint32, mv[b]);
          ppb[(b << 6) + (wv << 3) + jj] = pk;
        }
      }
      __syncthreads();
      if (tid < 128) {
        const int jb = tid & 7, b = tid >> 3;
        const int cf = n0v + jb;
        float bmv = -3.0e38f; int bmi = 0x7fffffff;
#pragma unroll
        for (int w = 0; w < 8; ++w) {
          ull pk = ppb[(b << 6) + (w << 3) + jb];
          float pv = __builtin_bit_cast(float, (uint32)pk);
          int pi = (int)(pk >> 32);
          if (pv > bmv || (pv == bmv && pi < bmi)) { bmv = pv; bmi = pi; }
        }
        const float nv = bmv + em[((((size_t)b << 7) + t) << 10) + cf];
        store_bypass_f(av_ring + (size_t)(t & 3) * 16384 + (size_t)cf * 16 + b, nv);
        store_bypass_i(bp + ((size_t)t << 14) + ((size_t)b << 10) + cf, bmi);
        if (t == stb2[b]) store_bypass_f(av_last + ((size_t)b << 10) + cf, nv);
        asm volatile("s_waitcnt vmcnt(0)" ::: "memory");
      }
      __syncthreads();
      if (tid == 0) cnt_add(cntV + ((((t & 3) << 3) + (v & 7)) << 4));
    }
    if (tid == 0) cnt_add(vdone);
    // ---- backtrace: block v==0; wait for all 128 vit blocks ----
    if (v == 0) {
      if (tid == 0) {
        while (load_bypass_u32(vdone) < 128u) __builtin_amdgcn_s_sleep(1);
      }
      __syncthreads();
      const int wv = tid >> 6, lh = tid & 63;
      const int hb = lh >> 5, hl = lh & 31;
      const int b = wv * 2 + hb;
      const int tbb = y_lens[b] - 1;
      for (int t2 = tbb + 1 + hl; t2 < 128; t2 += 32) out_crf[(b << 7) + t2] = 0.f;
      float bv = -3.0e38f; int bi = 0x7fffffff;
      for (int q = 0; q < 32; ++q) {
        const int i = (q << 5) + hl;
        const float val = load_bypass_f(av_last + ((size_t)b << 10) + i);
        if (val > bv || (val == bv && i < bi)) { bv = val; bi = i; }
      }
#pragma unroll
      for (int d = 1; d < 32; d <<= 1) {
        float ov = __shfl_xor(bv, d, 32);
        int oi = __shfl_xor(bi, d, 32);
        if (ov > bv || (ov == bv && oi < bi)) { bv = ov; bi = oi; }
      }
      if (hl == 0) {
        int sx = bi;
        out_crf[(b << 7) + tbb] = (float)sx;
        for (int t2 = tbb - 1; t2 >= 0; --t2) {
          sx = load_bypass_i(bp + ((size_t)(t2 + 1) << 14) + ((size_t)b << 10) + sx);
          out_crf[(b << 7) + t2] = (float)sx;
        }
      }
    }
  } else {
    // ======== approx: one block per batch, block-local (512 thr, 4 i-quarters)
    const int b = bid - 136;
    const int tb = y_lens[b] - 1;
    const int j2 = tid & 127, h2 = tid >> 7;
    float* sua0 = (float*)SH;
    float* sua1 = sua0 + 104;
    int* sidxp = (int*)(sua0 + 208);
    int* sidxc = sidxp + 104;
    float* aps = (float*)(sidxc + 104);        // 3*104
    if (tid < 102) {
      float vv = expf(em_top[(size_t)(b * 128) * 102 + tid]);
      sua0[tid] = vv;
      if (tb == 0) ua_last[b * 102 + tid] = vv;
    }
    __syncthreads();
    for (int t = 1; t < 128; ++t) {
      if (tid < 102) sidxp[tid] = top_idx[((size_t)b * 128 + (t - 1)) * 102 + tid];
      else if (tid >= 256 && tid < 358)
        sidxc[tid - 256] = top_idx[((size_t)b * 128 + t) * 102 + (tid - 256)];
      __syncthreads();
      float acc2 = 0.f;
      float* up = (t & 1) ? sua0 : sua1;
      float* cur = (t & 1) ? sua1 : sua0;
      if (j2 < 102) {
        const int colc = sidxc[j2];
        const int ia = h2 * 26;
        const int ib2 = (ia + 26 < 102) ? ia + 26 : 102;
        for (int i = ia; i < ib2; ++i)
          acc2 += up[i] * bflo((uint32)expTb[(size_t)sidxp[i] * 1024 + colc]);
      }
      if (h2 > 0 && j2 < 102) aps[(h2 - 1) * 104 + j2] = acc2;
      __syncthreads();
      if (h2 == 0 && j2 < 102) {
        acc2 += aps[j2] + aps[104 + j2] + aps[208 + j2];
        const float e = em_top[((size_t)b * 128 + t) * 102 + j2];
        const float nv = acc2 * expf(e) * (1.0f / 102.0f);
        cur[j2] = nv;
        if (t == tb) ua_last[b * 102 + j2] = nv;
      }
      __syncthreads();
    }
  }
}

// ---------------- scalars & metrics ----
__device__ __forceinline__ float blk_sum(float v, float* rb, int tid) {
  rb[tid] = v; __syncthreads();
  for (int w = 128; w > 0; w >>= 1) { if (tid < w) rb[tid] += rb[tid + w]; __syncthreads(); }
  float r = rb[0]; __syncthreads();
  return r;
}

__global__ __launch_bounds__(256) void finalize_kernel(
    const float* __restrict__ emission, const float* __restrict__ transition,
    const float* __restrict__ u_last, const float* __restrict__ ua_last,
    const float* __restrict__ row_max, const float* __restrict__ row_lse,
    const int* __restrict__ sm_pred, const int* __restrict__ y,
    const int* __restrict__ y_lens, float* __restrict__ d_out) {
  __shared__ float rb[256];
  __shared__ float sZ[16], sZa[16], sLogy[16];
  const int tid = threadIdx.x;
  const float* out_crf = d_out + 1;
  for (int b = 0; b < 16; ++b) {
    const int tb = y_lens[b] - 1;
    float p = 0.f;
    for (int i = tid; i < 1024; i += 256) p += u_last[(size_t)b * 1024 + i];
    p = blk_sum(p, rb, tid);
    if (tid == 0) sZ[b] = logf(p) + (float)tb * 6.931471805599453f;  // ln(1024)
    float q = 0.f;
    for (int i = tid; i < 102; i += 256) q += ua_last[(size_t)b * 102 + i];
    q = blk_sum(q, rb, tid);
    if (tid == 0) sZa[b] = logf(q) + (float)tb * 4.624972813284271f;  // ln(102)
  }
  if (tid < 16) sLogy[tid] = 0.f;
  __syncthreads();
  float a_local = 0, a_maxp = 0, c_sup = 0, c_pred = 0, c_ov = 0, c_match = 0;
  float s_predc = 0, s_ov = 0, s_match = 0;
  for (int r = tid; r < 2048; r += 256) {
    const int b = r >> 7, t = r & 127;
    const int L = y_lens[b];
    if (t < L) {
      const int yv = y[r];
      const float em_y = emission[(size_t)r * 1024 + yv];
      const float lse = row_lse[r];
      a_local += em_y - lse;
      a_maxp += expf(row_max[r] - lse);
      float term = em_y;
      if (t < L - 1) term += transition[(size_t)yv * 1024 + y[r + 1]];
      atomicAdd(&sLogy[b], term);
      const float ypos = (yv > 0) ? 1.f : 0.f;
      c_sup += ypos;
      const int cs = (int)out_crf[r];
      c_pred += (cs > 0) ? 1.f : 0.f;
      c_ov += ((cs > 0) && (yv > 0)) ? 1.f : 0.f;
      c_match += (cs == yv) ? 1.f : 0.f;
      const int ss = sm_pred[r];
      s_predc += (ss > 0) ? 1.f : 0.f;
      s_ov += ((ss > 0) && (yv > 0)) ? 1.f : 0.f;
      s_match += (ss == yv) ? 1.f : 0.f;
    }
  }
  __syncthreads();
  a_local = blk_sum(a_local, rb, tid);
  a_maxp = blk_sum(a_maxp, rb, tid);
  c_sup = blk_sum(c_sup, rb, tid);
  c_pred = blk_sum(c_pred, rb, tid);
  c_ov = blk_sum(c_ov, rb, tid);
  c_match = blk_sum(c_match, rb, tid);
  s_predc = blk_sum(s_predc, rb, tid);
  s_ov = blk_sum(s_ov, rb, tid);
  s_match = blk_sum(s_match, rb, tid);
  if (tid == 0) {
    float tl = 0.f;
    for (int b = 0; b < 16; ++b) tl += (float)y_lens[b];
    float mZ = 0, mZa = 0, dE = 0, dA = 0;
    for (int b = 0; b < 16; ++b) {
      mZ += sZ[b]; mZa += sZa[b];
      dE += sLogy[b] - sZ[b];
      dA += sLogy[b] - sZa[b];
    }
    mZ *= (1.f / 16.f); mZa *= (1.f / 16.f);
    const float sle = -dE * (1.f / 16.f);
    const float sla = -dA * (1.f / 16.f);
    const float slocal = a_local / tl;
    const float maxp = a_maxp / tl;
    const float loss = sla + 0.1f * slocal;
    const float crf_acc = c_match / tl;
    const float crf_prec = (c_pred > 0.f) ? (c_ov / fmaxf(c_pred, 1.f)) : 0.f;
    const float crf_recl = c_ov / fmaxf(c_sup, 1.f);
    const float crf_f1 = (crf_prec > 0.f)
        ? (2.f * crf_prec * crf_recl / fmaxf(crf_prec + crf_recl, 1e-12f)) : 0.f;
    const float sm_acc = s_match / tl;
    const float sm_prec = (s_predc > 0.f) ? (s_ov / fmaxf(s_predc, 1.f)) : 0.f;
    const float sm_recl = s_ov / fmaxf(c_sup, 1.f);
    const float sm_f1 = (sm_prec > 0.f)
        ? (2.f * sm_prec * sm_recl / fmaxf(sm_prec + sm_recl, 1e-12f)) : 0.f;
    d_out[0] = loss;
    d_out[2049] = mZ;
    d_out[2050] = mZa;
    d_out[2051] = sle;
    d_out[2052] = slocal;
    d_out[2053] = maxp;
    d_out[2054] = crf_acc;
    d_out[2055] = crf_f1;
    d_out[2056] = sm_acc;
    d_out[2057] = sm_f1;
  }
}

extern "C" void kernel_launch(void* const* d_in, const int* in_sizes, int n_in,
                              void* d_out, int out_size, void* d_ws, size_t ws_size,
                              hipStream_t stream) {
  const float* x = (const float*)d_in[0];
  const float* stm = (const float*)d_in[1];
  const int* y = (const int*)d_in[2];
  const int* yl = (const int*)d_in[3];
  float* out = (float*)d_out;
  float* ws = (float*)d_ws;

  float* emission = ws + OFF_EM;
  float* transition = ws + OFF_TR;
  u16* expTb = (u16*)(ws + OFF_EXPTB);
  u16* expTbT = (u16*)(ws + OFF_EXPTT);
  float* u_ring = ws + OFF_UPP;
  float* av_ring = ws + OFF_APP;
  float* u_last = ws + OFF_ULST;
  float* av_last = ws + OFF_ALST;
  float* ua_last = ws + OFF_UALST;
  float* em_top = ws + OFF_ETOP;
  int* top_idx = (int*)(ws + OFF_ITOP);
  float* row_max = ws + OFF_RMAX;
  float* row_lse = ws + OFF_RLSE;
  int* sm_pred = (int*)(ws + OFF_SMP);
  int* bp = (int*)(ws + OFF_BP);
  uint32* done = (uint32*)(ws + OFF_DONE);

  zero_kernel<<<4, 256, 0, stream>>>(done);
  gemm_kernel<<<dim3(48, 16), 256, 0, stream>>>(x, stm, emission, transition, expTb);
  transT_kernel<<<dim3(16, 16), 256, 0, stream>>>(expTb, expTbT);
  topk_kernel<<<2048, 256, 0, stream>>>(emission, em_top, top_idx, row_max, row_lse, sm_pred);
  scan_kernel<<<152, 512, 0, stream>>>(emission, transition, expTb, expTbT, em_top, top_idx,
                                       yl, u_ring, av_ring, u_last, av_last, ua_last,
                                       bp, done, out + 1);
  finalize_kernel<<<1, 256, 0, stream>>>(emission, transition, u_last, ua_last,
                                         row_max, row_lse, sm_pred, y, yl, out);
}

// Round 4
// 1886.509 us; speedup vs baseline: 1.0147x; 1.0084x over previous
//
#include <hip/hip_runtime.h>
#include <cstdint>
#include <cstddef>

typedef unsigned long long ull;
typedef unsigned int uint32;
typedef unsigned short u16;
typedef __attribute__((ext_vector_type(8))) short s8v;     // 8 bf16 (4 VGPR) MFMA frag
typedef __attribute__((ext_vector_type(4))) float f32x4;   // MFMA acc

// B=16, T=128, K=1024, D=768, KP=102
// R13 = R11 skeleton (verified passing) with ONE change: consumer staging
// loads switch from relaxed ATOMIC 8B loads (per-lane atomic-unit path,
// ~1M transactions/step -> ~7us/step serialization) to plain
// global_load_dwordx4 with sc1 (L1/L2-bypass, coalescer-eligible, 16B).
// Atomicity is unnecessary: the monotone counter publishes only after the
// producer's full vmcnt drain, so staged data is never concurrently written.
// Ordering: loads are issued after the poll's __syncthreads (cannot hoist);
// a s_waitcnt vmcnt(0) + sched_barrier(0) precedes the dependent LDS writes.

// ---- workspace layout (4-byte word offsets) ----
#define OFF_EM    ((size_t)0)         // emission   2048*1024 f32
#define OFF_TR    ((size_t)2097152)   // transition 1024*1024 f32
#define OFF_EXPTB ((size_t)3145728)   // expTb      [i][j] bf16
#define OFF_UPP   ((size_t)3670016)   // fwd ring   4 slots * (hi+lo bf16 planes [m][k])
#define OFF_APP   ((size_t)3735552)   // vit ring   4 slots * [i][b] f32
#define OFF_ULST  ((size_t)3801088)   // u at t=tb  16*1024 f32
#define OFF_ALST  ((size_t)3817472)   // av at t=tb 16*1024 f32
#define OFF_UALST ((size_t)3833856)   // ua at t=tb 16*102
#define OFF_ETOP  ((size_t)3835904)   // em_top 2048*102
#define OFF_ITOP  ((size_t)4044800)   // top_idx 2048*102
#define OFF_RMAX  ((size_t)4253696)
#define OFF_RLSE  ((size_t)4255744)
#define OFF_SMP   ((size_t)4257792)
#define OFF_BP    ((size_t)4259840)   // bp 128*16*1024 int
#define OFF_DONE  ((size_t)6356992)   // counters: fcnt 4*16 | vcnt 32*16 | vdone
#define OFF_EXPTT ((size_t)6367744)   // expTbT [j][i] bf16 (524288 words)

__device__ __forceinline__ u16 f2bf(float f) {
  uint32 u = __builtin_bit_cast(uint32, f);
  u = (u + 0x7fffu + ((u >> 16) & 1u)) >> 16;
  return (u16)u;
}
__device__ __forceinline__ float bflo(uint32 w) {
  return __builtin_bit_cast(float, w << 16);
}
__device__ __forceinline__ void bfsplit(float v, u16& h, u16& l) {
  h = f2bf(v);
  float rh = __builtin_bit_cast(float, ((uint32)h) << 16);
  l = f2bf(v - rh);
}

// ---- coherent (cross-XCD) access helpers: relaxed agent-scope atomics ----
__device__ __forceinline__ uint32 load_bypass_u32(const uint32* p) {
  return __hip_atomic_load(p, __ATOMIC_RELAXED, __HIP_MEMORY_SCOPE_AGENT);
}
__device__ __forceinline__ void store_bypass_u32(uint32* p, uint32 v) {
  __hip_atomic_store(p, v, __ATOMIC_RELAXED, __HIP_MEMORY_SCOPE_AGENT);
}
__device__ __forceinline__ void store_bypass_u16(u16* p, u16 v) {
  __hip_atomic_store(p, v, __ATOMIC_RELAXED, __HIP_MEMORY_SCOPE_AGENT);
}
__device__ __forceinline__ float load_bypass_f(const float* p) {
  return __hip_atomic_load(p, __ATOMIC_RELAXED, __HIP_MEMORY_SCOPE_AGENT);
}
__device__ __forceinline__ void store_bypass_f(float* p, float v) {
  __hip_atomic_store(p, v, __ATOMIC_RELAXED, __HIP_MEMORY_SCOPE_AGENT);
}
__device__ __forceinline__ void store_bypass_i(int* p, int v) {
  __hip_atomic_store(p, v, __ATOMIC_RELAXED, __HIP_MEMORY_SCOPE_AGENT);
}
__device__ __forceinline__ int load_bypass_i(const int* p) {
  return __hip_atomic_load(p, __ATOMIC_RELAXED, __HIP_MEMORY_SCOPE_AGENT);
}
__device__ __forceinline__ void cnt_add(uint32* p) {
  __hip_atomic_fetch_add(p, 1u, __ATOMIC_RELAXED, __HIP_MEMORY_SCOPE_AGENT);
}
// NON-atomic L1/L2-bypassing 16B load (sc1). Result arrives after a later
// s_waitcnt vmcnt(0); caller must fence before using the value.
__device__ __forceinline__ float4 ld_b128_sc1(const float4* p) {
  float4 r;
  asm volatile("global_load_dwordx4 %0, %1, off sc1" : "=v"(r) : "v"(p));
  return r;
}

// ---------------- GEMM: [x_emb; state] (3072x768) @ state^T -> 3072x1024 ----
__global__ __launch_bounds__(256) void gemm_kernel(
    const float* __restrict__ x, const float* __restrict__ stm,
    float* __restrict__ emission, float* __restrict__ transition,
    u16* __restrict__ expTb) {
  __shared__ float As[16][68];
  __shared__ float Bs[16][68];
  const int tid = threadIdx.x;
  const int tx = tid & 15, ty = tid >> 4;
  const int m0 = blockIdx.x * 64, n0 = blockIdx.y * 64;
  const int lr = tid >> 2;
  const int lc = (tid & 3) << 2;
  float acc[4][4] = {};
  const float* aptr;
  {
    int gr = m0 + lr;
    aptr = (gr < 2048) ? (x + (size_t)gr * 768) : (stm + (size_t)(gr - 2048) * 768);
  }
  const float* bptr = stm + (size_t)(n0 + lr) * 768;
  for (int k0 = 0; k0 < 768; k0 += 16) {
    float4 a4 = *(const float4*)(aptr + k0 + lc);
    float4 b4 = *(const float4*)(bptr + k0 + lc);
    __syncthreads();
    As[lc + 0][lr] = a4.x; As[lc + 1][lr] = a4.y; As[lc + 2][lr] = a4.z; As[lc + 3][lr] = a4.w;
    Bs[lc + 0][lr] = b4.x; Bs[lc + 1][lr] = b4.y; Bs[lc + 2][lr] = b4.z; Bs[lc + 3][lr] = b4.w;
    __syncthreads();
#pragma unroll
    for (int kk = 0; kk < 16; ++kk) {
      float a[4], b[4];
#pragma unroll
      for (int q = 0; q < 4; ++q) a[q] = As[kk][ty * 4 + q];
#pragma unroll
      for (int q = 0; q < 4; ++q) b[q] = Bs[kk][tx * 4 + q];
#pragma unroll
      for (int i2 = 0; i2 < 4; ++i2)
#pragma unroll
        for (int j2 = 0; j2 < 4; ++j2) acc[i2][j2] += a[i2] * b[j2];
    }
  }
  const float rs = 0.03608439182435161f;  // 1/sqrt(768)
#pragma unroll
  for (int i2 = 0; i2 < 4; ++i2) {
    int r = m0 + ty * 4 + i2;
#pragma unroll
    for (int j2 = 0; j2 < 4; ++j2) {
      int c = n0 + tx * 4 + j2;
      float v = acc[i2][j2] * rs;
      if (r < 2048) {
        emission[(size_t)r * 1024 + c] = v;
      } else {
        size_t o = (size_t)(r - 2048) * 1024 + c;
        transition[o] = v;
        expTb[o] = f2bf(expf(v));
      }
    }
  }
}

// ---------------- bf16 transpose: expTbT[j][i] = expTb[i][j] ----------------
__global__ __launch_bounds__(256) void transT_kernel(
    const u16* __restrict__ src, u16* __restrict__ dst) {
  __shared__ u16 tile[64][65];
  const int bx = blockIdx.x * 64, by = blockIdx.y * 64;
  const int tx = threadIdx.x & 63, ty4 = threadIdx.x >> 6;
  for (int rr = ty4; rr < 64; rr += 4)
    tile[rr][tx] = src[(size_t)(bx + rr) * 1024 + by + tx];
  __syncthreads();
  for (int rr = ty4; rr < 64; rr += 4)
    dst[(size_t)(by + rr) * 1024 + bx + tx] = tile[tx][rr];
}

// ---------------- per-row bitonic sort -> top-102 set, max, lse, argmax ----
__global__ __launch_bounds__(256) void topk_kernel(
    const float* __restrict__ emission, float* __restrict__ em_top,
    int* __restrict__ top_idx, float* __restrict__ row_max,
    float* __restrict__ row_lse, int* __restrict__ sm_pred) {
  __shared__ float v[1024];
  __shared__ int ix[1024];
  __shared__ float rb[256];
  const int row = blockIdx.x;
  const int tid = threadIdx.x;
  const float* e = emission + (size_t)row * 1024;
  for (int p = tid; p < 1024; p += 256) { v[p] = e[p]; ix[p] = p; }
  __syncthreads();
  for (int k = 2; k <= 1024; k <<= 1) {
    for (int j = k >> 1; j > 0; j >>= 1) {
      for (int p = tid; p < 1024; p += 256) {
        int l = p ^ j;
        if (l > p) {
          float va = v[p], vb = v[l];
          int ia = ix[p], ib = ix[l];
          bool aBefore = (va > vb) || (va == vb && ia < ib);
          bool up = ((p & k) == 0);
          if (up ? !aBefore : aBefore) { v[p] = vb; v[l] = va; ix[p] = ib; ix[l] = ia; }
        }
      }
      __syncthreads();
    }
  }
  float mx = v[0];
  float s = 0.f;
  for (int p = tid; p < 1024; p += 256) s += expf(v[p] - mx);
  rb[tid] = s; __syncthreads();
  for (int w = 128; w > 0; w >>= 1) { if (tid < w) rb[tid] += rb[tid + w]; __syncthreads(); }
  if (tid == 0) {
    row_max[row] = mx;
    row_lse[row] = mx + logf(rb[0]);
    sm_pred[row] = ix[0];
  }
  for (int p = tid; p < 102; p += 256) {
    em_top[(size_t)row * 102 + p] = v[p];
    top_idx[(size_t)row * 102 + p] = ix[p];
  }
}

// ---------------- zero the counter region (runs each launch) ----------------
__global__ __launch_bounds__(256) void zero_kernel(uint32* __restrict__ done) {
  const int idx = blockIdx.x * 256 + threadIdx.x;   // 4*256 = 1024 words
  store_bypass_u32(done + idx, 0u);
}

// ---------------- persistent all-batch scan ----------------
// grid 152 x 512: [0,8) fwd MFMA; [8,136) viterbi; [136,152) approx.
__global__ __launch_bounds__(512) void scan_kernel(
    const float* __restrict__ em, const float* __restrict__ tr,
    const u16* __restrict__ expTb, const u16* __restrict__ expTbT,
    const float* __restrict__ em_top, const int* __restrict__ top_idx,
    const int* __restrict__ y_lens,
    float* __restrict__ u_ring, float* __restrict__ av_ring,
    float* __restrict__ u_last, float* __restrict__ av_last,
    float* __restrict__ ua_last, int* __restrict__ bp,
    uint32* __restrict__ done, float* __restrict__ out_crf) {
  __shared__ ull SH[9232];                     // 73,856 B union (forces 1 block/CU)
  const int bid = blockIdx.x, tid = threadIdx.x;
  uint32* cntF = done;                         // fcnt[slot]      at done[slot*16]
  uint32* cntV = done + 64;                    // vcnt[slot][ln]  at done[64+(slot*8+ln)*16]
  uint32* vdone = done + 640;                  // single word

  if (bid < 8) {
    // ======== forward: block p owns cols [p*128, p*128+128), all 16 batches.
    const int p = bid;
    int* stbF = (int*)(SH + 8192);             // LDS byte 65536 (past A-stage)
    if (tid < 16) stbF[tid] = y_lens[tid] - 1;
    const int l = tid & 63;
    const int lm = l & 15, lq = l >> 4;
    const int w2 = (tid >> 6) & 3;             // compute waves 0..3 (tid<256)
    // ---- t = 0 init: u0 = exp(em[:,0,:]) ----
    if (tid < 256) {
      const int m = tid >> 4;
      const int nn = p * 128 + ((tid & 15) << 3);
      const float* e0 = em + ((size_t)m << 17) + nn;
      u16* rh = (u16*)u_ring;                  // slot 0
      const bool last0 = (y_lens[m] == 1);
#pragma unroll
      for (int q = 0; q < 8; ++q) {
        float v = expf(e0[q]);
        u16 h, lo2; bfsplit(v, h, lo2);
        store_bypass_u16(rh + m * 1024 + nn + q, h);
        store_bypass_u16(rh + 16384 + m * 1024 + nn + q, lo2);
        if (last0) u_last[(size_t)m * 1024 + nn + q] = v;
      }
      asm volatile("s_waitcnt vmcnt(0)" ::: "memory");   // drain in EVERY storing wave
    }
    __syncthreads();
    if (tid == 0) cnt_add(cntF + 0);
    const char* Ab = (const char*)SH;
    const int offh = (lm << 11) + (lq << 4);   // A frag: m=lane&15 row, k-group lane>>4
    const int axor = (lm & 7) << 4;            // LDS XOR swizzle (2048B rows)
    const int nbase = p * 128 + w2 * 32;
    const u16* bq0 = expTbT + ((size_t)(nbase + lm) << 10) + (lq << 3);
    const u16* bq1 = bq0 + (16 << 10);
    for (int t = 1; t < 128; ++t) {
      if (tid == 0) {
        const uint32 tgt = (uint32)((((t - 1) >> 2) + 1) * 8);
        const uint32* cp = cntF + (((t - 1) & 3) << 4);
        while (load_bypass_u32(cp) < tgt) __builtin_amdgcn_s_sleep(1);
      }
      __syncthreads();
      {  // stage A (hi/lo planes, 64 KB) ring -> LDS; 16B sc1 bypass loads
        const float4* src = (const float4*)(u_ring + (size_t)((t - 1) & 3) * 16384);
        float4 dbuf[8];
#pragma unroll
        for (int q = 0; q < 8; ++q) dbuf[q] = ld_b128_sc1(src + (q << 9) + tid);
        asm volatile("s_waitcnt vmcnt(0)" ::: "memory");
        __builtin_amdgcn_sched_barrier(0);
#pragma unroll
        for (int q = 0; q < 8; ++q) {
          const int ob = ((q << 9) + tid) << 4;
          *(float4*)((char*)SH + (ob ^ (((ob >> 11) & 7) << 4))) = dbuf[q];
        }
      }
      __syncthreads();
      if (tid < 256) {
        f32x4 acc0a = {0.f, 0.f, 0.f, 0.f}, acc0b = {0.f, 0.f, 0.f, 0.f};
        f32x4 acc1a = {0.f, 0.f, 0.f, 0.f}, acc1b = {0.f, 0.f, 0.f, 0.f};
        for (int k0 = 0; k0 < 1024; k0 += 64) {
          const int o0 = (offh + (k0 << 1)) ^ axor;
          const int o1 = (offh + ((k0 + 32) << 1)) ^ axor;
          s8v ah0 = *(const s8v*)(Ab + o0);
          s8v al0 = *(const s8v*)(Ab + 32768 + o0);
          s8v ah1 = *(const s8v*)(Ab + o1);
          s8v al1 = *(const s8v*)(Ab + 32768 + o1);
          s8v b00 = *(const s8v*)(bq0 + k0);
          s8v b10 = *(const s8v*)(bq1 + k0);
          s8v b01 = *(const s8v*)(bq0 + k0 + 32);
          s8v b11 = *(const s8v*)(bq1 + k0 + 32);
          acc0a = __builtin_amdgcn_mfma_f32_16x16x32_bf16(ah0, b00, acc0a, 0, 0, 0);
          acc1a = __builtin_amdgcn_mfma_f32_16x16x32_bf16(ah0, b10, acc1a, 0, 0, 0);
          acc0b = __builtin_amdgcn_mfma_f32_16x16x32_bf16(ah1, b01, acc0b, 0, 0, 0);
          acc1b = __builtin_amdgcn_mfma_f32_16x16x32_bf16(ah1, b11, acc1b, 0, 0, 0);
          acc0a = __builtin_amdgcn_mfma_f32_16x16x32_bf16(al0, b00, acc0a, 0, 0, 0);
          acc1a = __builtin_amdgcn_mfma_f32_16x16x32_bf16(al0, b10, acc1a, 0, 0, 0);
          acc0b = __builtin_amdgcn_mfma_f32_16x16x32_bf16(al1, b01, acc0b, 0, 0, 0);
          acc1b = __builtin_amdgcn_mfma_f32_16x16x32_bf16(al1, b11, acc1b, 0, 0, 0);
        }
        u16* rh = (u16*)(u_ring + (size_t)(t & 3) * 16384);
        const float sc = 1.0f / 1024.0f;
#pragma unroll
        for (int r = 0; r < 4; ++r) {
          const int m = (lq << 2) + r;         // C/D: col=lane&15, row=(lane>>4)*4+r
          const size_t erow = (((size_t)m << 7) + t) << 10;
          {
            const int n = nbase + lm;
            float v = (acc0a[r] + acc0b[r]) * sc * expf(em[erow + n]);
            u16 h, lo2; bfsplit(v, h, lo2);
            store_bypass_u16(rh + m * 1024 + n, h);
            store_bypass_u16(rh + 16384 + m * 1024 + n, lo2);
            if (t == stbF[m]) u_last[(size_t)m * 1024 + n] = v;
          }
          {
            const int n = nbase + 16 + lm;
            float v = (acc1a[r] + acc1b[r]) * sc * expf(em[erow + n]);
            u16 h, lo2; bfsplit(v, h, lo2);
            store_bypass_u16(rh + m * 1024 + n, h);
            store_bypass_u16(rh + 16384 + m * 1024 + n, lo2);
            if (t == stbF[m]) u_last[(size_t)m * 1024 + n] = v;
          }
        }
        asm volatile("s_waitcnt vmcnt(0)" ::: "memory");
      }
      __syncthreads();
      if (tid == 0) cnt_add(cntF + ((t & 3) << 4));
    }
  } else if (bid < 136) {
    // ======== viterbi: block v owns 8 cols (XCD-contiguous), all 16 batches.
    const int v = bid - 8;
    const int n0v = ((v & 7) << 7) + ((v >> 3) << 3);   // XCD v%8 gets cols [x*128,x*128+128)
    const int jj = tid & 7, g = tid >> 3;               // g in [0,64): 16 i's each
    const int col = n0v + jj;
    ull* ppb = (ull*)((char*)SH + 65536);               // partials [b][w][j] (val,idx)
    int* stb2 = (int*)((char*)SH + 73728);
    if (tid < 16) stb2[tid] = y_lens[tid] - 1;
    if (tid < 128) {                                    // t=0: av0 = em[:,0,:]
      const int jb = tid & 7, b = tid >> 3;
      const float e0 = em[((size_t)b << 17) + n0v + jb];
      store_bypass_f(av_ring + (size_t)(n0v + jb) * 16 + b, e0);
      if (y_lens[b] == 1) store_bypass_f(av_last + ((size_t)b << 10) + n0v + jb, e0);
      asm volatile("s_waitcnt vmcnt(0)" ::: "memory");  // drain in EVERY storing wave
    }
    __syncthreads();
    if (tid == 0) cnt_add(cntV + ((v & 7) << 4));       // slot 0, line v&7
    const char* stc = (const char*)SH;                  // staged av [i][16] f32, swizzled
    for (int t = 1; t < 128; ++t) {
      if (tid < 8) {
        const uint32 tgt = (uint32)((((t - 1) >> 2) + 1) * 16);
        const uint32* cp = cntV + (((((t - 1) & 3) << 3) + tid) << 4);
        while (load_bypass_u32(cp) < tgt) __builtin_amdgcn_s_sleep(1);
      }
      __syncthreads();
      {  // stage av (64 KB) ring -> LDS; 16B sc1 bypass loads, XOR-swizzled
        const float4* src = (const float4*)(av_ring + (size_t)((t - 1) & 3) * 16384);
        float4 dbuf[8];
#pragma unroll
        for (int q = 0; q < 8; ++q) dbuf[q] = ld_b128_sc1(src + (q << 9) + tid);
        asm volatile("s_waitcnt vmcnt(0)" ::: "memory");
        __builtin_amdgcn_sched_barrier(0);
#pragma unroll
        for (int q = 0; q < 8; ++q) {
          const int ob = ((q << 9) + tid) << 4;
          *(float4*)((char*)SH + (ob ^ (((ob >> 10) & 7) << 4))) = dbuf[q];
        }
      }
      __syncthreads();
      float mv[16]; int mi[16];
#pragma unroll
      for (int b = 0; b < 16; ++b) { mv[b] = -3.0e38f; mi[b] = 0x7fffffff; }
      const float* trc = tr + col;
      const int i0 = g << 4;
#pragma unroll 4
      for (int ii = 0; ii < 16; ++ii) {
        const int i = i0 + ii;
        const float tv = trc[(size_t)i << 10];
        const int ph = (i << 6) ^ (((i >> 4) & 7) << 4);
        const f32x4 s0 = *(const f32x4*)(stc + (ph ^ 0));
        const f32x4 s1 = *(const f32x4*)(stc + (ph ^ 16));
        const f32x4 s2 = *(const f32x4*)(stc + (ph ^ 32));
        const f32x4 s3 = *(const f32x4*)(stc + (ph ^ 48));
#pragma unroll
        for (int b = 0; b < 4; ++b) {
          float c0 = s0[b] + tv; if (c0 > mv[b])      { mv[b] = c0;      mi[b] = i; }
          float c1 = s1[b] + tv; if (c1 > mv[b + 4])  { mv[b + 4] = c1;  mi[b + 4] = i; }
          float c2 = s2[b] + tv; if (c2 > mv[b + 8])  { mv[b + 8] = c2;  mi[b + 8] = i; }
          float c3 = s3[b] + tv; if (c3 > mv[b + 12]) { mv[b + 12] = c3; mi[b + 12] = i; }
        }
      }
      // reduce over the wave's 8 g's (lane bits 3..5); ties -> lowest i
#pragma unroll
      for (int d = 8; d <= 32; d <<= 1) {
#pragma unroll
        for (int b = 0; b < 16; ++b) {
          float ov = __shfl_xor(mv[b], d);
          int oi = __shfl_xor(mi[b], d);
          if (ov > mv[b] || (ov == mv[b] && oi < mi[b])) { mv[b] = ov; mi[b] = oi; }
        }
      }
      if ((tid & 63) < 8) {
        const int wv = tid >> 6;
#pragma unroll
        for (int b = 0; b < 16; ++b) {
          ull pk = ((ull)(uint32)mi[b] << 32) | (ull)__builtin_bit_cast(uint32, mv[b]);
          ppb[(b << 6) + (wv << 3) + jj] = pk;
        }
      }
      __syncthreads();
      if (tid < 128) {
        const int jb = tid & 7, b = tid >> 3;
        const int cf = n0v + jb;
        float bmv = -3.0e38f; int bmi = 0x7fffffff;
#pragma unroll
        for (int w = 0; w < 8; ++w) {
          ull pk = ppb[(b << 6) + (w << 3) + jb];
          float pv = __builtin_bit_cast(float, (uint32)pk);
          int pi = (int)(pk >> 32);
          if (pv > bmv || (pv == bmv && pi < bmi)) { bmv = pv; bmi = pi; }
        }
        const float nv = bmv + em[((((size_t)b << 7) + t) << 10) + cf];
        store_bypass_f(av_ring + (size_t)(t & 3) * 16384 + (size_t)cf * 16 + b, nv);
        store_bypass_i(bp + ((size_t)t << 14) + ((size_t)b << 10) + cf, bmi);
        if (t == stb2[b]) store_bypass_f(av_last + ((size_t)b << 10) + cf, nv);
        asm volatile("s_waitcnt vmcnt(0)" ::: "memory");
      }
      __syncthreads();
      if (tid == 0) cnt_add(cntV + ((((t & 3) << 3) + (v & 7)) << 4));
    }
    if (tid == 0) cnt_add(vdone);
    // ---- backtrace: block v==0; wait for all 128 vit blocks ----
    if (v == 0) {
      if (tid == 0) {
        while (load_bypass_u32(vdone) < 128u) __builtin_amdgcn_s_sleep(1);
      }
      __syncthreads();
      const int wv = tid >> 6, lh = tid & 63;
      const int hb = lh >> 5, hl = lh & 31;
      const int b = wv * 2 + hb;
      const int tbb = y_lens[b] - 1;
      for (int t2 = tbb + 1 + hl; t2 < 128; t2 += 32) out_crf[(b << 7) + t2] = 0.f;
      float bv = -3.0e38f; int bi = 0x7fffffff;
      for (int q = 0; q < 32; ++q) {
        const int i = (q << 5) + hl;
        const float val = load_bypass_f(av_last + ((size_t)b << 10) + i);
        if (val > bv || (val == bv && i < bi)) { bv = val; bi = i; }
      }
#pragma unroll
      for (int d = 1; d < 32; d <<= 1) {
        float ov = __shfl_xor(bv, d, 32);
        int oi = __shfl_xor(bi, d, 32);
        if (ov > bv || (ov == bv && oi < bi)) { bv = ov; bi = oi; }
      }
      if (hl == 0) {
        int sx = bi;
        out_crf[(b << 7) + tbb] = (float)sx;
        for (int t2 = tbb - 1; t2 >= 0; --t2) {
          sx = load_bypass_i(bp + ((size_t)(t2 + 1) << 14) + ((size_t)b << 10) + sx);
          out_crf[(b << 7) + t2] = (float)sx;
        }
      }
    }
  } else {
    // ======== approx: one block per batch, block-local (512 thr, 4 i-quarters)
    const int b = bid - 136;
    const int tb = y_lens[b] - 1;
    const int j2 = tid & 127, h2 = tid >> 7;
    float* sua0 = (float*)SH;
    float* sua1 = sua0 + 104;
    int* sidxp = (int*)(sua0 + 208);
    int* sidxc = sidxp + 104;
    float* aps = (float*)(sidxc + 104);        // 3*104
    if (tid < 102) {
      float vv = expf(em_top[(size_t)(b * 128) * 102 + tid]);
      sua0[tid] = vv;
      if (tb == 0) ua_last[b * 102 + tid] = vv;
    }
    __syncthreads();
    for (int t = 1; t < 128; ++t) {
      if (tid < 102) sidxp[tid] = top_idx[((size_t)b * 128 + (t - 1)) * 102 + tid];
      else if (tid >= 256 && tid < 358)
        sidxc[tid - 256] = top_idx[((size_t)b * 128 + t) * 102 + (tid - 256)];
      __syncthreads();
      float acc2 = 0.f;
      float* up = (t & 1) ? sua0 : sua1;
      float* cur = (t & 1) ? sua1 : sua0;
      if (j2 < 102) {
        const int colc = sidxc[j2];
        const int ia = h2 * 26;
        const int ib2 = (ia + 26 < 102) ? ia + 26 : 102;
        for (int i = ia; i < ib2; ++i)
          acc2 += up[i] * bflo((uint32)expTb[(size_t)sidxp[i] * 1024 + colc]);
      }
      if (h2 > 0 && j2 < 102) aps[(h2 - 1) * 104 + j2] = acc2;
      __syncthreads();
      if (h2 == 0 && j2 < 102) {
        acc2 += aps[j2] + aps[104 + j2] + aps[208 + j2];
        const float e = em_top[((size_t)b * 128 + t) * 102 + j2];
        const float nv = acc2 * expf(e) * (1.0f / 102.0f);
        cur[j2] = nv;
        if (t == tb) ua_last[b * 102 + j2] = nv;
      }
      __syncthreads();
    }
  }
}

// ---------------- scalars & metrics ----
__device__ __forceinline__ float blk_sum(float v, float* rb, int tid) {
  rb[tid] = v; __syncthreads();
  for (int w = 128; w > 0; w >>= 1) { if (tid < w) rb[tid] += rb[tid + w]; __syncthreads(); }
  float r = rb[0]; __syncthreads();
  return r;
}

__global__ __launch_bounds__(256) void finalize_kernel(
    const float* __restrict__ emission, const float* __restrict__ transition,
    const float* __restrict__ u_last, const float* __restrict__ ua_last,
    const float* __restrict__ row_max, const float* __restrict__ row_lse,
    const int* __restrict__ sm_pred, const int* __restrict__ y,
    const int* __restrict__ y_lens, float* __restrict__ d_out) {
  __shared__ float rb[256];
  __shared__ float sZ[16], sZa[16], sLogy[16];
  const int tid = threadIdx.x;
  const float* out_crf = d_out + 1;
  for (int b = 0; b < 16; ++b) {
    const int tb = y_lens[b] - 1;
    float p = 0.f;
    for (int i = tid; i < 1024; i += 256) p += u_last[(size_t)b * 1024 + i];
    p = blk_sum(p, rb, tid);
    if (tid == 0) sZ[b] = logf(p) + (float)tb * 6.931471805599453f;  // ln(1024)
    float q = 0.f;
    for (int i = tid; i < 102; i += 256) q += ua_last[(size_t)b * 102 + i];
    q = blk_sum(q, rb, tid);
    if (tid == 0) sZa[b] = logf(q) + (float)tb * 4.624972813284271f;  // ln(102)
  }
  if (tid < 16) sLogy[tid] = 0.f;
  __syncthreads();
  float a_local = 0, a_maxp = 0, c_sup = 0, c_pred = 0, c_ov = 0, c_match = 0;
  float s_predc = 0, s_ov = 0, s_match = 0;
  for (int r = tid; r < 2048; r += 256) {
    const int b = r >> 7, t = r & 127;
    const int L = y_lens[b];
    if (t < L) {
      const int yv = y[r];
      const float em_y = emission[(size_t)r * 1024 + yv];
      const float lse = row_lse[r];
      a_local += em_y - lse;
      a_maxp += expf(row_max[r] - lse);
      float term = em_y;
      if (t < L - 1) term += transition[(size_t)yv * 1024 + y[r + 1]];
      atomicAdd(&sLogy[b], term);
      const float ypos = (yv > 0) ? 1.f : 0.f;
      c_sup += ypos;
      const int cs = (int)out_crf[r];
      c_pred += (cs > 0) ? 1.f : 0.f;
      c_ov += ((cs > 0) && (yv > 0)) ? 1.f : 0.f;
      c_match += (cs == yv) ? 1.f : 0.f;
      const int ss = sm_pred[r];
      s_predc += (ss > 0) ? 1.f : 0.f;
      s_ov += ((ss > 0) && (yv > 0)) ? 1.f : 0.f;
      s_match += (ss == yv) ? 1.f : 0.f;
    }
  }
  __syncthreads();
  a_local = blk_sum(a_local, rb, tid);
  a_maxp = blk_sum(a_maxp, rb, tid);
  c_sup = blk_sum(c_sup, rb, tid);
  c_pred = blk_sum(c_pred, rb, tid);
  c_ov = blk_sum(c_ov, rb, tid);
  c_match = blk_sum(c_match, rb, tid);
  s_predc = blk_sum(s_predc, rb, tid);
  s_ov = blk_sum(s_ov, rb, tid);
  s_match = blk_sum(s_match, rb, tid);
  if (tid == 0) {
    float tl = 0.f;
    for (int b = 0; b < 16; ++b) tl += (float)y_lens[b];
    float mZ = 0, mZa = 0, dE = 0, dA = 0;
    for (int b = 0; b < 16; ++b) {
      mZ += sZ[b]; mZa += sZa[b];
      dE += sLogy[b] - sZ[b];
      dA += sLogy[b] - sZa[b];
    }
    mZ *= (1.f / 16.f); mZa *= (1.f / 16.f);
    const float sle = -dE * (1.f / 16.f);
    const float sla = -dA * (1.f / 16.f);
    const float slocal = a_local / tl;
    const float maxp = a_maxp / tl;
    const float loss = sla + 0.1f * slocal;
    const float crf_acc = c_match / tl;
    const float crf_prec = (c_pred > 0.f) ? (c_ov / fmaxf(c_pred, 1.f)) : 0.f;
    const float crf_recl = c_ov / fmaxf(c_sup, 1.f);
    const float crf_f1 = (crf_prec > 0.f)
        ? (2.f * crf_prec * crf_recl / fmaxf(crf_prec + crf_recl, 1e-12f)) : 0.f;
    const float sm_acc = s_match / tl;
    const float sm_prec = (s_predc > 0.f) ? (s_ov / fmaxf(s_predc, 1.f)) : 0.f;
    const float sm_recl = s_ov / fmaxf(c_sup, 1.f);
    const float sm_f1 = (sm_prec > 0.f)
        ? (2.f * sm_prec * sm_recl / fmaxf(sm_prec + sm_recl, 1e-12f)) : 0.f;
    d_out[0] = loss;
    d_out[2049] = mZ;
    d_out[2050] = mZa;
    d_out[2051] = sle;
    d_out[2052] = slocal;
    d_out[2053] = maxp;
    d_out[2054] = crf_acc;
    d_out[2055] = crf_f1;
    d_out[2056] = sm_acc;
    d_out[2057] = sm_f1;
  }
}

extern "C" void kernel_launch(void* const* d_in, const int* in_sizes, int n_in,
                              void* d_out, int out_size, void* d_ws, size_t ws_size,
                              hipStream_t stream) {
  const float* x = (const float*)d_in[0];
  const float* stm = (const float*)d_in[1];
  const int* y = (const int*)d_in[2];
  const int* yl = (const int*)d_in[3];
  float* out = (float*)d_out;
  float* ws = (float*)d_ws;

  float* emission = ws + OFF_EM;
  float* transition = ws + OFF_TR;
  u16* expTb = (u16*)(ws + OFF_EXPTB);
  u16* expTbT = (u16*)(ws + OFF_EXPTT);
  float* u_ring = ws + OFF_UPP;
  float* av_ring = ws + OFF_APP;
  float* u_last = ws + OFF_ULST;
  float* av_last = ws + OFF_ALST;
  float* ua_last = ws + OFF_UALST;
  float* em_top = ws + OFF_ETOP;
  int* top_idx = (int*)(ws + OFF_ITOP);
  float* row_max = ws + OFF_RMAX;
  float* row_lse = ws + OFF_RLSE;
  int* sm_pred = (int*)(ws + OFF_SMP);
  int* bp = (int*)(ws + OFF_BP);
  uint32* done = (uint32*)(ws + OFF_DONE);

  zero_kernel<<<4, 256, 0, stream>>>(done);
  gemm_kernel<<<dim3(48, 16), 256, 0, stream>>>(x, stm, emission, transition, expTb);
  transT_kernel<<<dim3(16, 16), 256, 0, stream>>>(expTb, expTbT);
  topk_kernel<<<2048, 256, 0, stream>>>(emission, em_top, top_idx, row_max, row_lse, sm_pred);
  scan_kernel<<<152, 512, 0, stream>>>(emission, transition, expTb, expTbT, em_top, top_idx,
                                       yl, u_ring, av_ring, u_last, av_last, ua_last,
                                       bp, done, out + 1);
  finalize_kernel<<<1, 256, 0, stream>>>(emission, transition, u_last, ua_last,
                                         row_max, row_lse, sm_pred, y, yl, out);
}